// Round 3
// baseline (190.408 us; speedup 1.0000x reference)
//
#include <hip/hip_runtime.h>

// ---------------------------------------------------------------------------
// TrajectoryAttention: x@Wq.T+bq / Wk / Wv -> RoPE(q,k) -> causal attn -> @Wo.T+bo
// B=2, T=2048, C=1024, H=16, D=64.  All matmuls bf16 MFMA (fp32 accum).
// R3: 2-phase double-buffered prefetch (stage next tile before compute,
//     single barrier per step) in GEMMs and attention.
// ---------------------------------------------------------------------------

typedef unsigned short u16;
typedef unsigned int u32;
typedef __bf16 bf16_t;
typedef bf16_t bf16x8 __attribute__((ext_vector_type(8)));
typedef float f32x4 __attribute__((ext_vector_type(4)));
typedef float f32x16 __attribute__((ext_vector_type(16)));

__device__ __forceinline__ u16 f2bf(float f) {
  union { float f; unsigned u; } v; v.f = f;
  return (u16)((v.u + 0x7FFFu + ((v.u >> 16) & 1u)) >> 16);  // RNE
}

__device__ __forceinline__ void gload_lds16(const void* g, void* l) {
  __builtin_amdgcn_global_load_lds(
      (const __attribute__((address_space(1))) void*)g,
      (__attribute__((address_space(3))) void*)l, 16, 0, 0);
}

// ---------------------------------------------------------------------------
__global__ __launch_bounds__(256) void cvt_kernel(const float* __restrict__ in,
                                                  u16* __restrict__ out, int n4) {
  int i = blockIdx.x * blockDim.x + threadIdx.x;
  if (i < n4) {
    float4 f = ((const float4*)in)[i];
    ushort4 o;
    o.x = f2bf(f.x); o.y = f2bf(f.y); o.z = f2bf(f.z); o.w = f2bf(f.w);
    ((ushort4*)out)[i] = o;
  }
}

// one launch converts all 4 weight matrices (y selects)
__global__ __launch_bounds__(256) void cvtw_kernel(const float* __restrict__ w0,
                                                   const float* __restrict__ w1,
                                                   const float* __restrict__ w2,
                                                   const float* __restrict__ w3,
                                                   u16* __restrict__ o0,
                                                   u16* __restrict__ o1,
                                                   u16* __restrict__ o2,
                                                   u16* __restrict__ o3) {
  int i = blockIdx.x * blockDim.x + threadIdx.x;  // 262144 per matrix
  const float* in = (blockIdx.y == 0) ? w0 : (blockIdx.y == 1) ? w1
                   : (blockIdx.y == 2) ? w2 : w3;
  u16* out = (blockIdx.y == 0) ? o0 : (blockIdx.y == 1) ? o1
            : (blockIdx.y == 2) ? o2 : o3;
  float4 f = ((const float4*)in)[i];
  ushort4 o;
  o.x = f2bf(f.x); o.y = f2bf(f.y); o.z = f2bf(f.z); o.w = f2bf(f.w);
  ((ushort4*)out)[i] = o;
}

__global__ __launch_bounds__(256) void rope_table_kernel(float* __restrict__ tab) {
  int idx = blockIdx.x * blockDim.x + threadIdx.x;  // T*32 = 65536
  int t = idx >> 5, i = idx & 31;
  float freq = powf(10000.0f, -(float)i * (1.0f / 32.0f));
  float a = (float)t * freq;
  tab[t * 64 + i] = cosf(a);
  tab[t * 64 + 32 + i] = sinf(a);
}

// ---------------------------------------------------------------------------
// Stage one 128x64 A-tile + 128x64 B-tile into LDS (slot-swizzled source).
__device__ __forceinline__ void stage_ab(const u16* __restrict__ A,
                                         const u16* __restrict__ Bt,
                                         int m0, int n0, int k0,
                                         u16* lA, u16* lB, int tid) {
#pragma unroll
  for (int r = 0; r < 4; ++r) {
    int ch = r * 256 + tid;
    int row = ch >> 3, s = ch & 7;
    gload_lds16(A + (size_t)(m0 + row) * 1024 + k0 + ((s ^ (row & 7)) << 3),
                lA + ch * 8);
  }
#pragma unroll
  for (int r = 0; r < 4; ++r) {
    int ch = r * 256 + tid;
    int row = ch >> 3, s = ch & 7;
    gload_lds16(Bt + (size_t)(n0 + row) * 1024 + k0 + ((s ^ (row & 7)) << 3),
                lB + ch * 8);
  }
}

// 2-phase double-buffered GEMM mainloop: C[128x128] = A[128xK] * Bt[128xK]^T.
// lA/lB hold TWO 128x64 buffers each (offset 8192 u16).
__device__ __forceinline__ void gemm_tile_db(const u16* __restrict__ A,
                                             const u16* __restrict__ Bt,
                                             int m0, int n0, u16* lA, u16* lB,
                                             f32x4 acc[4][4]) {
  const int tid = threadIdx.x;
  const int l = tid & 63;
  const int wr = tid >> 7, wc = (tid >> 6) & 1;

#pragma unroll
  for (int m = 0; m < 4; ++m)
#pragma unroll
    for (int n = 0; n < 4; ++n)
      acc[m][n] = (f32x4){0.f, 0.f, 0.f, 0.f};

  stage_ab(A, Bt, m0, n0, 0, lA, lB, tid);
  __syncthreads();  // drains prologue staging

  int cur = 0;
  for (int t = 0; t < 16; ++t) {
    if (t + 1 < 16)  // issue next-tile staging BEFORE compute (overlap)
      stage_ab(A, Bt, m0, n0, (t + 1) * 64, lA + (cur ^ 1) * 8192,
               lB + (cur ^ 1) * 8192, tid);
    const u16* pA = lA + cur * 8192;
    const u16* pB = lB + cur * 8192;
#pragma unroll
    for (int kk = 0; kk < 2; ++kk) {
      bf16x8 af[4], bf[4];
#pragma unroll
      for (int m = 0; m < 4; ++m) {
        int row = wr * 64 + m * 16 + (l & 15);
        int slot = (kk * 4 + (l >> 4)) ^ (row & 7);
        af[m] = *(const bf16x8*)(pA + row * 64 + slot * 8);
      }
#pragma unroll
      for (int n = 0; n < 4; ++n) {
        int row = wc * 64 + n * 16 + (l & 15);
        int slot = (kk * 4 + (l >> 4)) ^ (row & 7);
        bf[n] = *(const bf16x8*)(pB + row * 64 + slot * 8);
      }
#pragma unroll
      for (int m = 0; m < 4; ++m)
#pragma unroll
        for (int n = 0; n < 4; ++n)
          acc[m][n] =
              __builtin_amdgcn_mfma_f32_16x16x32_bf16(af[m], bf[n], acc[m][n], 0, 0, 0);
    }
    __syncthreads();  // drains next-tile vmcnt + protects buf reuse
    cur ^= 1;
  }
}

// ---------------------------------------------------------------------------
// QKV projection + bias + RoPE.  z=0:Q (scaled 1/8)  z=1:K  z=2:V ([B,H,D,T])
__global__ __launch_bounds__(256) void qkv_kernel(
    const u16* __restrict__ xb, const u16* __restrict__ Wqb,
    const u16* __restrict__ Wkb, const u16* __restrict__ Wvb,
    const float* __restrict__ bq, const float* __restrict__ bk,
    const float* __restrict__ bv, const float* __restrict__ tab,
    u16* __restrict__ Q, u16* __restrict__ Kr, u16* __restrict__ Vt) {
  __shared__ __align__(16) u16 lA[2 * 128 * 64];
  __shared__ __align__(16) u16 lB[2 * 128 * 64];
  const int z = blockIdx.z;
  const u16* W = (z == 0) ? Wqb : ((z == 1) ? Wkb : Wvb);
  const float* bias = (z == 0) ? bq : ((z == 1) ? bk : bv);
  const int m0 = blockIdx.y * 128, n0 = blockIdx.x * 128;

  f32x4 acc[4][4];
  gemm_tile_db(xb, W, m0, n0, lA, lB, acc);

  const int tid = threadIdx.x, l = tid & 63;
  const int wr = tid >> 7, wc = (tid >> 6) & 1;
#pragma unroll
  for (int m = 0; m < 4; ++m)
#pragma unroll
    for (int n = 0; n < 4; ++n)
#pragma unroll
      for (int jr = 0; jr < 4; ++jr) {
        int gr = m0 + wr * 64 + m * 16 + ((l >> 4) << 2) + jr;  // token row
        int gc = n0 + wc * 64 + n * 16 + (l & 15);              // channel
        int b = gr >> 11, t = gr & 2047;
        int h = gc >> 6, d = gc & 63;
        float val = acc[m][n][jr] + bias[gc];
        if (z == 2) {
          Vt[(((size_t)((b * 16 + h) * 64 + d)) << 11) + t] = f2bf(val);
        } else {
          float p = acc[m][n ^ 2][jr] + bias[gc ^ 32];  // partner channel d^32
          float cs = tab[t * 64 + (d & 31)];
          float sn = tab[t * 64 + 32 + (d & 31)];
          float rot = (d < 32) ? -p : p;
          float o = val * cs + rot * sn;
          if (z == 0) o *= 0.125f;  // fold 1/sqrt(64) into Q
          u16* dst = (z == 0) ? Q : Kr;
          dst[((((size_t)(b * 16 + h)) << 11) + t) * 64 + d] = f2bf(o);
        }
      }
}

// ---------------------------------------------------------------------------
// Flash attention (causal), swapped-operand 32x32 MFMA, P in registers,
// double-buffered K/V staging with single barrier per tile.
__global__ __launch_bounds__(128) void attn_kernel(const u16* __restrict__ Q,
                                                   const u16* __restrict__ K,
                                                   const u16* __restrict__ Vt,
                                                   u16* __restrict__ out) {
  __shared__ __align__(16) u16 lK[2][64 * 64];
  __shared__ __align__(16) u16 lV[2][64 * 64];
  const int tid = threadIdx.x, l = tid & 63, w = tid >> 6;
  const int n = blockIdx.x;
  const int xcd = n & 7, j = n >> 3;
  const int bh = xcd * 4 + (j & 3);   // 0..31
  const int qt = j >> 2;              // 0..31
  const int b = bh >> 4, h = bh & 15;
  const int lq = l & 31, hl = l >> 5;
  const int q0w = qt * 64 + w * 32;
  const int qg = q0w + lq;  // this lane's global q row

  const u16* qbase = Q + ((((size_t)bh) << 11) + qg) * 64 + hl * 8;
  bf16x8 qf[4];
#pragma unroll
  for (int kd = 0; kd < 4; ++kd) qf[kd] = *(const bf16x8*)(qbase + kd * 16);

  const f32x16 z16 = {0.f, 0.f, 0.f, 0.f, 0.f, 0.f, 0.f, 0.f,
                      0.f, 0.f, 0.f, 0.f, 0.f, 0.f, 0.f, 0.f};
  f32x16 oacc[2];  // O^T: rows d, col q = lq
  oacc[0] = z16; oacc[1] = z16;
  float mi = -1e30f, li = 0.f;

  const int nt = qt + 1;

  // stage K [64 kv][64 d] and Vt [64 d][64 kv] for tile `it` into buf
#define STAGE_KV(it_, buf_)                                                        \
  {                                                                                \
    _Pragma("unroll") for (int r = 0; r < 4; ++r) {                                \
      int ch = r * 128 + tid;                                                      \
      int row = ch >> 3, s = ch & 7;                                               \
      gload_lds16(                                                                 \
          K + ((((size_t)bh) << 11) + (it_) * 64 + row) * 64 + ((s ^ (row & 7)) << 3), \
          &lK[buf_][0] + ch * 8);                                                  \
    }                                                                              \
    _Pragma("unroll") for (int r = 0; r < 4; ++r) {                                \
      int ch = r * 128 + tid;                                                      \
      int row = ch >> 3, s = ch & 7;                                               \
      gload_lds16(                                                                 \
          Vt + ((((size_t)bh) * 64 + row) << 11) + (it_) * 64 + ((s ^ (row & 7)) << 3), \
          &lV[buf_][0] + ch * 8);                                                  \
    }                                                                              \
  }

  STAGE_KV(0, 0);
  __syncthreads();
  int cur = 0;

  for (int it = 0; it < nt; ++it) {
    const int kv0 = it * 64;
    if (it + 1 < nt) STAGE_KV(it + 1, cur ^ 1);  // prefetch next tile
    const u16* pK = &lK[cur][0];
    const u16* pV = &lV[cur][0];

    // ---- S^T = K Q^T : sacc[g] rows = kv (32g..), cols = q ----
    f32x16 sacc[2];
    sacc[0] = z16; sacc[1] = z16;
#pragma unroll
    for (int g = 0; g < 2; ++g) {
      int row = g * 32 + lq;
      int sw = row & 7;
#pragma unroll
      for (int kd = 0; kd < 4; ++kd) {
        bf16x8 kf = *(const bf16x8*)(pK + row * 64 + (((kd * 2 + hl) ^ sw) << 3));
        sacc[g] = __builtin_amdgcn_mfma_f32_32x32x16_bf16(kf, qf[kd], sacc[g], 0, 0, 0);
      }
    }

    // ---- causal mask (only final tile of this warp triggers) ----
    if (kv0 + 63 > q0w) {
#pragma unroll
      for (int g = 0; g < 2; ++g)
#pragma unroll
        for (int r = 0; r < 16; ++r) {
          int kv = kv0 + g * 32 + (r & 3) + ((r >> 2) << 3) + hl * 4;
          if (kv > qg) sacc[g][r] = -1e30f;
        }
    }

    // ---- online softmax ----
    float mx[16];
#pragma unroll
    for (int r = 0; r < 16; ++r) mx[r] = fmaxf(sacc[0][r], sacc[1][r]);
#pragma unroll
    for (int s = 8; s > 0; s >>= 1)
#pragma unroll
      for (int r = 0; r < s; ++r) mx[r] = fmaxf(mx[r], mx[r + s]);
    float mt = fmaxf(mx[0], __shfl_xor(mx[0], 32, 64));
    float mn = fmaxf(mi, mt);
    float al = __expf(mi - mn);
    mi = mn;
#pragma unroll
    for (int g = 0; g < 2; ++g)
#pragma unroll
      for (int r = 0; r < 16; ++r) sacc[g][r] = __expf(sacc[g][r] - mn);
    float sm[16];
#pragma unroll
    for (int r = 0; r < 16; ++r) sm[r] = sacc[0][r] + sacc[1][r];
#pragma unroll
    for (int s = 8; s > 0; s >>= 1)
#pragma unroll
      for (int r = 0; r < s; ++r) sm[r] += sm[r + s];
    float rs = sm[0] + __shfl_xor(sm[0], 32, 64);
    li = li * al + rs;
#pragma unroll
    for (int dblk = 0; dblk < 2; ++dblk)
#pragma unroll
      for (int r = 0; r < 16; ++r) oacc[dblk][r] *= al;

    // ---- P -> bf16 pairs; build PV B-fragments via cross-half exchange ----
    u32 pw[2][8], px[2][8];
#pragma unroll
    for (int g = 0; g < 2; ++g)
#pragma unroll
      for (int i = 0; i < 8; ++i) {
        union { bf16_t h2[2]; u32 u; } pk;
        pk.h2[0] = (bf16_t)sacc[g][2 * i];
        pk.h2[1] = (bf16_t)sacc[g][2 * i + 1];
        pw[g][i] = pk.u;
      }
#pragma unroll
    for (int g = 0; g < 2; ++g)
#pragma unroll
      for (int i = 0; i < 8; ++i)
        px[g][i] = (u32)__shfl_xor((int)pw[g][i], 32, 64);

    bf16x8 pfrag[4];  // B-frag for kv chunk km*16: col=q, k=kv (hl*8+j)
#pragma unroll
    for (int km = 0; km < 4; ++km) {
      const int g = km >> 1, o = (km & 1) * 4;
      union { u32 u[4]; bf16x8 v; } f;
      f.u[0] = hl ? px[g][o + 2] : pw[g][o + 0];
      f.u[1] = hl ? px[g][o + 3] : pw[g][o + 1];
      f.u[2] = hl ? pw[g][o + 2] : px[g][o + 0];
      f.u[3] = hl ? pw[g][o + 3] : px[g][o + 1];
      pfrag[km] = f.v;
    }

    // ---- O^T += V^T P^T ----
#pragma unroll
    for (int dblk = 0; dblk < 2; ++dblk) {
      int row = dblk * 32 + lq;
      int sw = row & 7;
#pragma unroll
      for (int km = 0; km < 4; ++km) {
        bf16x8 vf = *(const bf16x8*)(pV + row * 64 + (((km * 2 + hl) ^ sw) << 3));
        oacc[dblk] = __builtin_amdgcn_mfma_f32_32x32x16_bf16(vf, pfrag[km], oacc[dblk], 0, 0, 0);
      }
    }
    __syncthreads();  // drains prefetch vmcnt + protects buf reuse
    cur ^= 1;
  }
#undef STAGE_KV

  // ---- write O^T / li to At[B,T,C] (bf16) ----
  const float inv = 1.0f / li;
  const size_t rowbase = ((size_t)(b * 2048 + qg)) * 1024 + h * 64;
#pragma unroll
  for (int dblk = 0; dblk < 2; ++dblk)
#pragma unroll
    for (int grp = 0; grp < 4; ++grp) {
      ushort4 st;
      st.x = f2bf(oacc[dblk][grp * 4 + 0] * inv);
      st.y = f2bf(oacc[dblk][grp * 4 + 1] * inv);
      st.z = f2bf(oacc[dblk][grp * 4 + 2] * inv);
      st.w = f2bf(oacc[dblk][grp * 4 + 3] * inv);
      *(ushort4*)((u16*)out + rowbase + dblk * 32 + grp * 8 + hl * 4) = st;
    }
}

// ---------------------------------------------------------------------------
__global__ __launch_bounds__(256) void outproj_kernel(const u16* __restrict__ attn,
                                                      const u16* __restrict__ Wob,
                                                      const float* __restrict__ bo,
                                                      float* __restrict__ out) {
  __shared__ __align__(16) u16 lA[2 * 128 * 64];
  __shared__ __align__(16) u16 lB[2 * 128 * 64];
  const int m0 = blockIdx.y * 128, n0 = blockIdx.x * 128;
  f32x4 acc[4][4];
  gemm_tile_db(attn, Wob, m0, n0, lA, lB, acc);
  const int tid = threadIdx.x, l = tid & 63;
  const int wr = tid >> 7, wc = (tid >> 6) & 1;
#pragma unroll
  for (int m = 0; m < 4; ++m)
#pragma unroll
    for (int n = 0; n < 4; ++n)
#pragma unroll
      for (int jr = 0; jr < 4; ++jr) {
        int gr = m0 + wr * 64 + m * 16 + ((l >> 4) << 2) + jr;
        int gc = n0 + wc * 64 + n * 16 + (l & 15);
        out[(size_t)gr * 1024 + gc] = acc[m][n][jr] + bo[gc];
      }
}

// ---------------------------------------------------------------------------
extern "C" void kernel_launch(void* const* d_in, const int* in_sizes, int n_in,
                              void* d_out, int out_size, void* d_ws, size_t ws_size,
                              hipStream_t stream) {
  const float* x  = (const float*)d_in[0];
  const float* Wq = (const float*)d_in[1];
  const float* bq = (const float*)d_in[2];
  const float* Wk = (const float*)d_in[3];
  const float* bk = (const float*)d_in[4];
  const float* Wv = (const float*)d_in[5];
  const float* bv = (const float*)d_in[6];
  const float* Wo = (const float*)d_in[7];
  const float* bo = (const float*)d_in[8];
  float* out = (float*)d_out;

  char* ws = (char*)d_ws;
  u16* xb  = (u16*)(ws);                          // 8 MB
  u16* Wqb = (u16*)(ws + (8ull << 20));           // 2 MB
  u16* Wkb = (u16*)(ws + (10ull << 20));          // 2 MB
  u16* Wvb = (u16*)(ws + (12ull << 20));          // 2 MB
  u16* Wob = (u16*)(ws + (14ull << 20));          // 2 MB
  u16* Qr  = (u16*)(ws + (16ull << 20));          // 8 MB  [B,H,T,D] (pre-scaled)
  u16* Kr  = (u16*)(ws + (24ull << 20));          // 8 MB  [B,H,T,D]
  u16* Vt  = (u16*)(ws + (32ull << 20));          // 8 MB  [B,H,D,T]
  u16* At  = (u16*)(ws + (40ull << 20));          // 8 MB  attn out bf16 [B,T,C]
  float* tab = (float*)(ws + (48ull << 20));      // 512 KB rope table

  cvt_kernel<<<dim3(4096), dim3(256), 0, stream>>>(x, xb, 1048576);
  cvtw_kernel<<<dim3(1024, 4), dim3(256), 0, stream>>>(Wq, Wk, Wv, Wo,
                                                       Wqb, Wkb, Wvb, Wob);
  rope_table_kernel<<<dim3(256), dim3(256), 0, stream>>>(tab);

  qkv_kernel<<<dim3(8, 32, 3), dim3(256), 0, stream>>>(xb, Wqb, Wkb, Wvb, bq, bk, bv,
                                                       tab, Qr, Kr, Vt);
  attn_kernel<<<dim3(1024), dim3(128), 0, stream>>>(Qr, Kr, Vt, At);
  outproj_kernel<<<dim3(8, 32), dim3(256), 0, stream>>>(At, Wob, bo, out);
}

// Round 4
// 172.962 us; speedup vs baseline: 1.1009x; 1.1009x over previous
//
#include <hip/hip_runtime.h>

// ---------------------------------------------------------------------------
// TrajectoryAttention: x@Wq.T+bq / Wk / Wv -> RoPE(q,k) -> causal attn -> @Wo.T+bo
// B=2, T=2048, C=1024, H=16, D=64.  All matmuls bf16 MFMA (fp32 accum).
// R4: double-buffered pipeline with COUNTED vmcnt(8) + raw s_barrier
//     (never drain vmcnt to 0 in the main loop) in GEMMs and attention.
// ---------------------------------------------------------------------------

typedef unsigned short u16;
typedef unsigned int u32;
typedef __bf16 bf16_t;
typedef bf16_t bf16x8 __attribute__((ext_vector_type(8)));
typedef float f32x4 __attribute__((ext_vector_type(4)));
typedef float f32x16 __attribute__((ext_vector_type(16)));

__device__ __forceinline__ u16 f2bf(float f) {
  union { float f; unsigned u; } v; v.f = f;
  return (u16)((v.u + 0x7FFFu + ((v.u >> 16) & 1u)) >> 16);  // RNE
}

__device__ __forceinline__ void gload_lds16(const void* g, void* l) {
  __builtin_amdgcn_global_load_lds(
      (const __attribute__((address_space(1))) void*)g,
      (__attribute__((address_space(3))) void*)l, 16, 0, 0);
}

// ---------------------------------------------------------------------------
__global__ __launch_bounds__(256) void cvt_kernel(const float* __restrict__ in,
                                                  u16* __restrict__ out, int n4) {
  int i = blockIdx.x * blockDim.x + threadIdx.x;
  if (i < n4) {
    float4 f = ((const float4*)in)[i];
    ushort4 o;
    o.x = f2bf(f.x); o.y = f2bf(f.y); o.z = f2bf(f.z); o.w = f2bf(f.w);
    ((ushort4*)out)[i] = o;
  }
}

__global__ __launch_bounds__(256) void cvtw_kernel(const float* __restrict__ w0,
                                                   const float* __restrict__ w1,
                                                   const float* __restrict__ w2,
                                                   const float* __restrict__ w3,
                                                   u16* __restrict__ o0,
                                                   u16* __restrict__ o1,
                                                   u16* __restrict__ o2,
                                                   u16* __restrict__ o3) {
  int i = blockIdx.x * blockDim.x + threadIdx.x;  // 262144 per matrix
  const float* in = (blockIdx.y == 0) ? w0 : (blockIdx.y == 1) ? w1
                   : (blockIdx.y == 2) ? w2 : w3;
  u16* out = (blockIdx.y == 0) ? o0 : (blockIdx.y == 1) ? o1
            : (blockIdx.y == 2) ? o2 : o3;
  float4 f = ((const float4*)in)[i];
  ushort4 o;
  o.x = f2bf(f.x); o.y = f2bf(f.y); o.z = f2bf(f.z); o.w = f2bf(f.w);
  ((ushort4*)out)[i] = o;
}

__global__ __launch_bounds__(256) void rope_table_kernel(float* __restrict__ tab) {
  int idx = blockIdx.x * blockDim.x + threadIdx.x;  // T*32 = 65536
  int t = idx >> 5, i = idx & 31;
  float freq = powf(10000.0f, -(float)i * (1.0f / 32.0f));
  float a = (float)t * freq;
  tab[t * 64 + i] = cosf(a);
  tab[t * 64 + 32 + i] = sinf(a);
}

// ---------------------------------------------------------------------------
// Stage one 128x64 A-tile + 128x64 B-tile into LDS (8 gload_lds / thread).
__device__ __forceinline__ void stage_ab(const u16* __restrict__ A,
                                         const u16* __restrict__ Bt,
                                         int m0, int n0, int k0,
                                         u16* lA, u16* lB, int tid) {
#pragma unroll
  for (int r = 0; r < 4; ++r) {
    int ch = r * 256 + tid;
    int row = ch >> 3, s = ch & 7;
    gload_lds16(A + (size_t)(m0 + row) * 1024 + k0 + ((s ^ (row & 7)) << 3),
                lA + ch * 8);
  }
#pragma unroll
  for (int r = 0; r < 4; ++r) {
    int ch = r * 256 + tid;
    int row = ch >> 3, s = ch & 7;
    gload_lds16(Bt + (size_t)(n0 + row) * 1024 + k0 + ((s ^ (row & 7)) << 3),
                lB + ch * 8);
  }
}

// Double-buffered GEMM mainloop with counted vmcnt:
//   stage(t+1); s_waitcnt vmcnt(8); s_barrier; compute(t); s_barrier
// Tile t+1's 8 loads stay in flight across the whole compute phase.
__device__ __forceinline__ void gemm_tile_db(const u16* __restrict__ A,
                                             const u16* __restrict__ Bt,
                                             int m0, int n0, u16* lA, u16* lB,
                                             f32x4 acc[4][4]) {
  const int tid = threadIdx.x;
  const int l = tid & 63;
  const int wr = tid >> 7, wc = (tid >> 6) & 1;

#pragma unroll
  for (int m = 0; m < 4; ++m)
#pragma unroll
    for (int n = 0; n < 4; ++n)
      acc[m][n] = (f32x4){0.f, 0.f, 0.f, 0.f};

  stage_ab(A, Bt, m0, n0, 0, lA, lB, tid);  // prologue: tile 0 in flight

  int cur = 0;
  for (int t = 0; t < 16; ++t) {
    if (t + 1 < 16) {
      stage_ab(A, Bt, m0, n0, (t + 1) * 64, lA + (cur ^ 1) * 8192,
               lB + (cur ^ 1) * 8192, tid);
      asm volatile("s_waitcnt vmcnt(8)" ::: "memory");  // tile t landed
    } else {
      asm volatile("s_waitcnt vmcnt(0)" ::: "memory");
    }
    __builtin_amdgcn_s_barrier();  // all waves' tile-t loads resident

    const u16* pA = lA + cur * 8192;
    const u16* pB = lB + cur * 8192;
#pragma unroll
    for (int kk = 0; kk < 2; ++kk) {
      bf16x8 af[4], bf[4];
#pragma unroll
      for (int m = 0; m < 4; ++m) {
        int row = wr * 64 + m * 16 + (l & 15);
        int slot = (kk * 4 + (l >> 4)) ^ (row & 7);
        af[m] = *(const bf16x8*)(pA + row * 64 + slot * 8);
      }
#pragma unroll
      for (int n = 0; n < 4; ++n) {
        int row = wc * 64 + n * 16 + (l & 15);
        int slot = (kk * 4 + (l >> 4)) ^ (row & 7);
        bf[n] = *(const bf16x8*)(pB + row * 64 + slot * 8);
      }
#pragma unroll
      for (int m = 0; m < 4; ++m)
#pragma unroll
        for (int n = 0; n < 4; ++n)
          acc[m][n] =
              __builtin_amdgcn_mfma_f32_16x16x32_bf16(af[m], bf[n], acc[m][n], 0, 0, 0);
    }
    __builtin_amdgcn_s_barrier();  // all waves done reading buf cur
    cur ^= 1;
  }
}

// ---------------------------------------------------------------------------
// QKV projection + bias + RoPE.  z=0:Q (scaled 1/8)  z=1:K  z=2:V ([B,H,D,T])
__global__ __launch_bounds__(256) void qkv_kernel(
    const u16* __restrict__ xb, const u16* __restrict__ Wqb,
    const u16* __restrict__ Wkb, const u16* __restrict__ Wvb,
    const float* __restrict__ bq, const float* __restrict__ bk,
    const float* __restrict__ bv, const float* __restrict__ tab,
    u16* __restrict__ Q, u16* __restrict__ Kr, u16* __restrict__ Vt) {
  __shared__ __align__(16) u16 lA[2 * 128 * 64];
  __shared__ __align__(16) u16 lB[2 * 128 * 64];
  const int z = blockIdx.z;
  const u16* W = (z == 0) ? Wqb : ((z == 1) ? Wkb : Wvb);
  const float* bias = (z == 0) ? bq : ((z == 1) ? bk : bv);
  const int m0 = blockIdx.y * 128, n0 = blockIdx.x * 128;

  f32x4 acc[4][4];
  gemm_tile_db(xb, W, m0, n0, lA, lB, acc);

  const int tid = threadIdx.x, l = tid & 63;
  const int wr = tid >> 7, wc = (tid >> 6) & 1;
#pragma unroll
  for (int m = 0; m < 4; ++m)
#pragma unroll
    for (int n = 0; n < 4; ++n)
#pragma unroll
      for (int jr = 0; jr < 4; ++jr) {
        int gr = m0 + wr * 64 + m * 16 + ((l >> 4) << 2) + jr;  // token row
        int gc = n0 + wc * 64 + n * 16 + (l & 15);              // channel
        int b = gr >> 11, t = gr & 2047;
        int h = gc >> 6, d = gc & 63;
        float val = acc[m][n][jr] + bias[gc];
        if (z == 2) {
          Vt[(((size_t)((b * 16 + h) * 64 + d)) << 11) + t] = f2bf(val);
        } else {
          float p = acc[m][n ^ 2][jr] + bias[gc ^ 32];  // partner channel d^32
          float cs = tab[t * 64 + (d & 31)];
          float sn = tab[t * 64 + 32 + (d & 31)];
          float rot = (d < 32) ? -p : p;
          float o = val * cs + rot * sn;
          if (z == 0) o *= 0.125f;  // fold 1/sqrt(64) into Q
          u16* dst = (z == 0) ? Q : Kr;
          dst[((((size_t)(b * 16 + h)) << 11) + t) * 64 + d] = f2bf(o);
        }
      }
}

// ---------------------------------------------------------------------------
// Flash attention (causal), swapped-operand 32x32 MFMA, P in registers,
// double-buffered K/V staging with counted vmcnt + raw barriers.
__global__ __launch_bounds__(128) void attn_kernel(const u16* __restrict__ Q,
                                                   const u16* __restrict__ K,
                                                   const u16* __restrict__ Vt,
                                                   u16* __restrict__ out) {
  __shared__ __align__(16) u16 lK[2][64 * 64];
  __shared__ __align__(16) u16 lV[2][64 * 64];
  const int tid = threadIdx.x, l = tid & 63, w = tid >> 6;
  const int n = blockIdx.x;
  const int xcd = n & 7, j = n >> 3;
  const int bh = xcd * 4 + (j & 3);   // 0..31
  const int qt = j >> 2;              // 0..31
  const int b = bh >> 4, h = bh & 15;
  const int lq = l & 31, hl = l >> 5;
  const int q0w = qt * 64 + w * 32;
  const int qg = q0w + lq;  // this lane's global q row

  const u16* qbase = Q + ((((size_t)bh) << 11) + qg) * 64 + hl * 8;
  bf16x8 qf[4];
#pragma unroll
  for (int kd = 0; kd < 4; ++kd) qf[kd] = *(const bf16x8*)(qbase + kd * 16);

  const f32x16 z16 = {0.f, 0.f, 0.f, 0.f, 0.f, 0.f, 0.f, 0.f,
                      0.f, 0.f, 0.f, 0.f, 0.f, 0.f, 0.f, 0.f};
  f32x16 oacc[2];  // O^T: rows d, col q = lq
  oacc[0] = z16; oacc[1] = z16;
  float mi = -1e30f, li = 0.f;

  const int nt = qt + 1;

  // stage K [64 kv][64 d] and Vt [64 d][64 kv] for tile `it` into buf (8 loads)
#define STAGE_KV(it_, buf_)                                                        \
  {                                                                                \
    _Pragma("unroll") for (int r = 0; r < 4; ++r) {                                \
      int ch = r * 128 + tid;                                                      \
      int row = ch >> 3, s = ch & 7;                                               \
      gload_lds16(                                                                 \
          K + ((((size_t)bh) << 11) + (it_) * 64 + row) * 64 + ((s ^ (row & 7)) << 3), \
          &lK[buf_][0] + ch * 8);                                                  \
    }                                                                              \
    _Pragma("unroll") for (int r = 0; r < 4; ++r) {                                \
      int ch = r * 128 + tid;                                                      \
      int row = ch >> 3, s = ch & 7;                                               \
      gload_lds16(                                                                 \
          Vt + ((((size_t)bh) * 64 + row) << 11) + (it_) * 64 + ((s ^ (row & 7)) << 3), \
          &lV[buf_][0] + ch * 8);                                                  \
    }                                                                              \
  }

  STAGE_KV(0, 0);  // prologue: tile 0 in flight
  int cur = 0;

  for (int it = 0; it < nt; ++it) {
    const int kv0 = it * 64;
    if (it + 1 < nt) {
      STAGE_KV(it + 1, cur ^ 1);
      asm volatile("s_waitcnt vmcnt(8)" ::: "memory");  // tile it landed
    } else {
      asm volatile("s_waitcnt vmcnt(0)" ::: "memory");
    }
    __builtin_amdgcn_s_barrier();

    const u16* pK = &lK[cur][0];
    const u16* pV = &lV[cur][0];

    // ---- S^T = K Q^T : sacc[g] rows = kv (32g..), cols = q ----
    f32x16 sacc[2];
    sacc[0] = z16; sacc[1] = z16;
#pragma unroll
    for (int g = 0; g < 2; ++g) {
      int row = g * 32 + lq;
      int sw = row & 7;
#pragma unroll
      for (int kd = 0; kd < 4; ++kd) {
        bf16x8 kf = *(const bf16x8*)(pK + row * 64 + (((kd * 2 + hl) ^ sw) << 3));
        sacc[g] = __builtin_amdgcn_mfma_f32_32x32x16_bf16(kf, qf[kd], sacc[g], 0, 0, 0);
      }
    }

    // ---- causal mask (only final tile of this warp triggers) ----
    if (kv0 + 63 > q0w) {
#pragma unroll
      for (int g = 0; g < 2; ++g)
#pragma unroll
        for (int r = 0; r < 16; ++r) {
          int kv = kv0 + g * 32 + (r & 3) + ((r >> 2) << 3) + hl * 4;
          if (kv > qg) sacc[g][r] = -1e30f;
        }
    }

    // ---- online softmax ----
    float mx[16];
#pragma unroll
    for (int r = 0; r < 16; ++r) mx[r] = fmaxf(sacc[0][r], sacc[1][r]);
#pragma unroll
    for (int s = 8; s > 0; s >>= 1)
#pragma unroll
      for (int r = 0; r < s; ++r) mx[r] = fmaxf(mx[r], mx[r + s]);
    float mt = fmaxf(mx[0], __shfl_xor(mx[0], 32, 64));
    float mn = fmaxf(mi, mt);
    float al = __expf(mi - mn);
    mi = mn;
#pragma unroll
    for (int g = 0; g < 2; ++g)
#pragma unroll
      for (int r = 0; r < 16; ++r) sacc[g][r] = __expf(sacc[g][r] - mn);
    float sm[16];
#pragma unroll
    for (int r = 0; r < 16; ++r) sm[r] = sacc[0][r] + sacc[1][r];
#pragma unroll
    for (int s = 8; s > 0; s >>= 1)
#pragma unroll
      for (int r = 0; r < s; ++r) sm[r] += sm[r + s];
    float rs = sm[0] + __shfl_xor(sm[0], 32, 64);
    li = li * al + rs;
#pragma unroll
    for (int dblk = 0; dblk < 2; ++dblk)
#pragma unroll
      for (int r = 0; r < 16; ++r) oacc[dblk][r] *= al;

    // ---- P -> bf16 pairs; build PV B-fragments via cross-half exchange ----
    u32 pw[2][8], px[2][8];
#pragma unroll
    for (int g = 0; g < 2; ++g)
#pragma unroll
      for (int i = 0; i < 8; ++i) {
        union { bf16_t h2[2]; u32 u; } pk;
        pk.h2[0] = (bf16_t)sacc[g][2 * i];
        pk.h2[1] = (bf16_t)sacc[g][2 * i + 1];
        pw[g][i] = pk.u;
      }
#pragma unroll
    for (int g = 0; g < 2; ++g)
#pragma unroll
      for (int i = 0; i < 8; ++i)
        px[g][i] = (u32)__shfl_xor((int)pw[g][i], 32, 64);

    bf16x8 pfrag[4];  // B-frag for kv chunk km*16: col=q, k=kv (hl*8+j)
#pragma unroll
    for (int km = 0; km < 4; ++km) {
      const int g = km >> 1, o = (km & 1) * 4;
      union { u32 u[4]; bf16x8 v; } f;
      f.u[0] = hl ? px[g][o + 2] : pw[g][o + 0];
      f.u[1] = hl ? px[g][o + 3] : pw[g][o + 1];
      f.u[2] = hl ? pw[g][o + 2] : px[g][o + 0];
      f.u[3] = hl ? pw[g][o + 3] : px[g][o + 1];
      pfrag[km] = f.v;
    }

    // ---- O^T += V^T P^T ----
#pragma unroll
    for (int dblk = 0; dblk < 2; ++dblk) {
      int row = dblk * 32 + lq;
      int sw = row & 7;
#pragma unroll
      for (int km = 0; km < 4; ++km) {
        bf16x8 vf = *(const bf16x8*)(pV + row * 64 + (((km * 2 + hl) ^ sw) << 3));
        oacc[dblk] = __builtin_amdgcn_mfma_f32_32x32x16_bf16(vf, pfrag[km], oacc[dblk], 0, 0, 0);
      }
    }
    __builtin_amdgcn_s_barrier();  // all waves done reading buf cur
    cur ^= 1;
  }
#undef STAGE_KV

  // ---- write O^T / li to At[B,T,C] (bf16) ----
  const float inv = 1.0f / li;
  const size_t rowbase = ((size_t)(b * 2048 + qg)) * 1024 + h * 64;
#pragma unroll
  for (int dblk = 0; dblk < 2; ++dblk)
#pragma unroll
    for (int grp = 0; grp < 4; ++grp) {
      ushort4 st;
      st.x = f2bf(oacc[dblk][grp * 4 + 0] * inv);
      st.y = f2bf(oacc[dblk][grp * 4 + 1] * inv);
      st.z = f2bf(oacc[dblk][grp * 4 + 2] * inv);
      st.w = f2bf(oacc[dblk][grp * 4 + 3] * inv);
      *(ushort4*)((u16*)out + rowbase + dblk * 32 + grp * 8 + hl * 4) = st;
    }
}

// ---------------------------------------------------------------------------
__global__ __launch_bounds__(256) void outproj_kernel(const u16* __restrict__ attn,
                                                      const u16* __restrict__ Wob,
                                                      const float* __restrict__ bo,
                                                      float* __restrict__ out) {
  __shared__ __align__(16) u16 lA[2 * 128 * 64];
  __shared__ __align__(16) u16 lB[2 * 128 * 64];
  const int m0 = blockIdx.y * 128, n0 = blockIdx.x * 128;
  f32x4 acc[4][4];
  gemm_tile_db(attn, Wob, m0, n0, lA, lB, acc);
  const int tid = threadIdx.x, l = tid & 63;
  const int wr = tid >> 7, wc = (tid >> 6) & 1;
#pragma unroll
  for (int m = 0; m < 4; ++m)
#pragma unroll
    for (int n = 0; n < 4; ++n)
#pragma unroll
      for (int jr = 0; jr < 4; ++jr) {
        int gr = m0 + wr * 64 + m * 16 + ((l >> 4) << 2) + jr;
        int gc = n0 + wc * 64 + n * 16 + (l & 15);
        out[(size_t)gr * 1024 + gc] = acc[m][n][jr] + bo[gc];
      }
}

// ---------------------------------------------------------------------------
extern "C" void kernel_launch(void* const* d_in, const int* in_sizes, int n_in,
                              void* d_out, int out_size, void* d_ws, size_t ws_size,
                              hipStream_t stream) {
  const float* x  = (const float*)d_in[0];
  const float* Wq = (const float*)d_in[1];
  const float* bq = (const float*)d_in[2];
  const float* Wk = (const float*)d_in[3];
  const float* bk = (const float*)d_in[4];
  const float* Wv = (const float*)d_in[5];
  const float* bv = (const float*)d_in[6];
  const float* Wo = (const float*)d_in[7];
  const float* bo = (const float*)d_in[8];
  float* out = (float*)d_out;

  char* ws = (char*)d_ws;
  u16* xb  = (u16*)(ws);                          // 8 MB
  u16* Wqb = (u16*)(ws + (8ull << 20));           // 2 MB
  u16* Wkb = (u16*)(ws + (10ull << 20));          // 2 MB
  u16* Wvb = (u16*)(ws + (12ull << 20));          // 2 MB
  u16* Wob = (u16*)(ws + (14ull << 20));          // 2 MB
  u16* Qr  = (u16*)(ws + (16ull << 20));          // 8 MB  [B,H,T,D] (pre-scaled)
  u16* Kr  = (u16*)(ws + (24ull << 20));          // 8 MB  [B,H,T,D]
  u16* Vt  = (u16*)(ws + (32ull << 20));          // 8 MB  [B,H,D,T]
  u16* At  = (u16*)(ws + (40ull << 20));          // 8 MB  attn out bf16 [B,T,C]
  float* tab = (float*)(ws + (48ull << 20));      // 512 KB rope table

  cvt_kernel<<<dim3(4096), dim3(256), 0, stream>>>(x, xb, 1048576);
  cvtw_kernel<<<dim3(1024, 4), dim3(256), 0, stream>>>(Wq, Wk, Wv, Wo,
                                                       Wqb, Wkb, Wvb, Wob);
  rope_table_kernel<<<dim3(256), dim3(256), 0, stream>>>(tab);

  qkv_kernel<<<dim3(8, 32, 3), dim3(256), 0, stream>>>(xb, Wqb, Wkb, Wvb, bq, bk, bv,
                                                       tab, Qr, Kr, Vt);
  attn_kernel<<<dim3(1024), dim3(128), 0, stream>>>(Qr, Kr, Vt, At);
  outproj_kernel<<<dim3(8, 32), dim3(256), 0, stream>>>(At, Wob, bo, out);
}

// Round 7
// 165.204 us; speedup vs baseline: 1.1526x; 1.0470x over previous
//
#include <hip/hip_runtime.h>

// ---------------------------------------------------------------------------
// TrajectoryAttention: x@Wq.T+bq / Wk / Wv -> RoPE(q,k) -> causal attn -> @Wo.T+bo
// B=2, T=2048, C=1024, H=16, D=64.  All matmuls bf16 MFMA (fp32 accum).
// R7: R6 with the permlane32_swap scalar reductions reverted to shfl_xor.
//     (permlane32_swap(x,x) aliases both operands to one physical VGPR: the
//      swap returns the SAME swapped value twice -> sum got partner doubled,
//      own half dropped -> li ~2x wrong. Max-reduce was immune; sum was not.)
//     Keeps: 4-wave QBLK=128 blocks, LPT order, active-gating, exp2-domain
//     softmax, defer-max, counted vmcnt, shfl-based pfrag exchange.
// ---------------------------------------------------------------------------

typedef unsigned short u16;
typedef unsigned int u32;
typedef __bf16 bf16_t;
typedef bf16_t bf16x8 __attribute__((ext_vector_type(8)));
typedef float f32x4 __attribute__((ext_vector_type(4)));
typedef float f32x16 __attribute__((ext_vector_type(16)));

#if __has_builtin(__builtin_amdgcn_exp2f)
#define EXP2(x) __builtin_amdgcn_exp2f(x)
#else
#define EXP2(x) exp2f(x)
#endif

__device__ __forceinline__ u16 f2bf(float f) {
  union { float f; unsigned u; } v; v.f = f;
  return (u16)((v.u + 0x7FFFu + ((v.u >> 16) & 1u)) >> 16);  // RNE
}

__device__ __forceinline__ void gload_lds16(const void* g, void* l) {
  __builtin_amdgcn_global_load_lds(
      (const __attribute__((address_space(1))) void*)g,
      (__attribute__((address_space(3))) void*)l, 16, 0, 0);
}

// ---------------------------------------------------------------------------
__global__ __launch_bounds__(256) void cvt_kernel(const float* __restrict__ in,
                                                  u16* __restrict__ out, int n4) {
  int i = blockIdx.x * blockDim.x + threadIdx.x;
  if (i < n4) {
    float4 f = ((const float4*)in)[i];
    ushort4 o;
    o.x = f2bf(f.x); o.y = f2bf(f.y); o.z = f2bf(f.z); o.w = f2bf(f.w);
    ((ushort4*)out)[i] = o;
  }
}

__global__ __launch_bounds__(256) void cvtw_kernel(const float* __restrict__ w0,
                                                   const float* __restrict__ w1,
                                                   const float* __restrict__ w2,
                                                   const float* __restrict__ w3,
                                                   u16* __restrict__ o0,
                                                   u16* __restrict__ o1,
                                                   u16* __restrict__ o2,
                                                   u16* __restrict__ o3) {
  int i = blockIdx.x * blockDim.x + threadIdx.x;  // 262144 per matrix
  const float* in = (blockIdx.y == 0) ? w0 : (blockIdx.y == 1) ? w1
                   : (blockIdx.y == 2) ? w2 : w3;
  u16* out = (blockIdx.y == 0) ? o0 : (blockIdx.y == 1) ? o1
            : (blockIdx.y == 2) ? o2 : o3;
  float4 f = ((const float4*)in)[i];
  ushort4 o;
  o.x = f2bf(f.x); o.y = f2bf(f.y); o.z = f2bf(f.z); o.w = f2bf(f.w);
  ((ushort4*)out)[i] = o;
}

__global__ __launch_bounds__(256) void rope_table_kernel(float* __restrict__ tab) {
  int idx = blockIdx.x * blockDim.x + threadIdx.x;  // T*32 = 65536
  int t = idx >> 5, i = idx & 31;
  float freq = powf(10000.0f, -(float)i * (1.0f / 32.0f));
  float a = (float)t * freq;
  tab[t * 64 + i] = cosf(a);
  tab[t * 64 + 32 + i] = sinf(a);
}

// ---------------------------------------------------------------------------
// Stage one 128x64 A-tile + 128x64 B-tile into LDS (8 gload_lds / thread).
__device__ __forceinline__ void stage_ab(const u16* __restrict__ A,
                                         const u16* __restrict__ Bt,
                                         int m0, int n0, int k0,
                                         u16* lA, u16* lB, int tid) {
#pragma unroll
  for (int r = 0; r < 4; ++r) {
    int ch = r * 256 + tid;
    int row = ch >> 3, s = ch & 7;
    gload_lds16(A + (size_t)(m0 + row) * 1024 + k0 + ((s ^ (row & 7)) << 3),
                lA + ch * 8);
  }
#pragma unroll
  for (int r = 0; r < 4; ++r) {
    int ch = r * 256 + tid;
    int row = ch >> 3, s = ch & 7;
    gload_lds16(Bt + (size_t)(n0 + row) * 1024 + k0 + ((s ^ (row & 7)) << 3),
                lB + ch * 8);
  }
}

// Double-buffered GEMM mainloop with counted vmcnt:
//   stage(t+1); s_waitcnt vmcnt(8); s_barrier; compute(t); s_barrier
__device__ __forceinline__ void gemm_tile_db(const u16* __restrict__ A,
                                             const u16* __restrict__ Bt,
                                             int m0, int n0, u16* lA, u16* lB,
                                             f32x4 acc[4][4]) {
  const int tid = threadIdx.x;
  const int l = tid & 63;
  const int wr = tid >> 7, wc = (tid >> 6) & 1;

#pragma unroll
  for (int m = 0; m < 4; ++m)
#pragma unroll
    for (int n = 0; n < 4; ++n)
      acc[m][n] = (f32x4){0.f, 0.f, 0.f, 0.f};

  stage_ab(A, Bt, m0, n0, 0, lA, lB, tid);  // prologue: tile 0 in flight

  int cur = 0;
  for (int t = 0; t < 16; ++t) {
    if (t + 1 < 16) {
      stage_ab(A, Bt, m0, n0, (t + 1) * 64, lA + (cur ^ 1) * 8192,
               lB + (cur ^ 1) * 8192, tid);
      asm volatile("s_waitcnt vmcnt(8)" ::: "memory");  // tile t landed
    } else {
      asm volatile("s_waitcnt vmcnt(0)" ::: "memory");
    }
    __builtin_amdgcn_s_barrier();

    const u16* pA = lA + cur * 8192;
    const u16* pB = lB + cur * 8192;
#pragma unroll
    for (int kk = 0; kk < 2; ++kk) {
      bf16x8 af[4], bf[4];
#pragma unroll
      for (int m = 0; m < 4; ++m) {
        int row = wr * 64 + m * 16 + (l & 15);
        int slot = (kk * 4 + (l >> 4)) ^ (row & 7);
        af[m] = *(const bf16x8*)(pA + row * 64 + slot * 8);
      }
#pragma unroll
      for (int n = 0; n < 4; ++n) {
        int row = wc * 64 + n * 16 + (l & 15);
        int slot = (kk * 4 + (l >> 4)) ^ (row & 7);
        bf[n] = *(const bf16x8*)(pB + row * 64 + slot * 8);
      }
#pragma unroll
      for (int m = 0; m < 4; ++m)
#pragma unroll
        for (int n = 0; n < 4; ++n)
          acc[m][n] =
              __builtin_amdgcn_mfma_f32_16x16x32_bf16(af[m], bf[n], acc[m][n], 0, 0, 0);
    }
    __builtin_amdgcn_s_barrier();
    cur ^= 1;
  }
}

// ---------------------------------------------------------------------------
// QKV projection + bias + RoPE.  z=0:Q (scaled 0.125*log2e)  z=1:K  z=2:V^T
__global__ __launch_bounds__(256) void qkv_kernel(
    const u16* __restrict__ xb, const u16* __restrict__ Wqb,
    const u16* __restrict__ Wkb, const u16* __restrict__ Wvb,
    const float* __restrict__ bq, const float* __restrict__ bk,
    const float* __restrict__ bv, const float* __restrict__ tab,
    u16* __restrict__ Q, u16* __restrict__ Kr, u16* __restrict__ Vt) {
  __shared__ __align__(16) u16 lA[2 * 128 * 64];
  __shared__ __align__(16) u16 lB[2 * 128 * 64];
  const int z = blockIdx.z;
  const u16* W = (z == 0) ? Wqb : ((z == 1) ? Wkb : Wvb);
  const float* bias = (z == 0) ? bq : ((z == 1) ? bk : bv);
  const int m0 = blockIdx.y * 128, n0 = blockIdx.x * 128;

  f32x4 acc[4][4];
  gemm_tile_db(xb, W, m0, n0, lA, lB, acc);

  const int tid = threadIdx.x, l = tid & 63;
  const int wr = tid >> 7, wc = (tid >> 6) & 1;
#pragma unroll
  for (int m = 0; m < 4; ++m)
#pragma unroll
    for (int n = 0; n < 4; ++n)
#pragma unroll
      for (int jr = 0; jr < 4; ++jr) {
        int gr = m0 + wr * 64 + m * 16 + ((l >> 4) << 2) + jr;  // token row
        int gc = n0 + wc * 64 + n * 16 + (l & 15);              // channel
        int b = gr >> 11, t = gr & 2047;
        int h = gc >> 6, d = gc & 63;
        float val = acc[m][n][jr] + bias[gc];
        if (z == 2) {
          Vt[(((size_t)((b * 16 + h) * 64 + d)) << 11) + t] = f2bf(val);
        } else {
          float p = acc[m][n ^ 2][jr] + bias[gc ^ 32];  // partner channel d^32
          float cs = tab[t * 64 + (d & 31)];
          float sn = tab[t * 64 + 32 + (d & 31)];
          float rot = (d < 32) ? -p : p;
          float o = val * cs + rot * sn;
          if (z == 0) o *= 0.18033688011112042f;  // 1/sqrt(64) * log2(e)
          u16* dst = (z == 0) ? Q : Kr;
          dst[((((size_t)(b * 16 + h)) << 11) + t) * 64 + d] = f2bf(o);
        }
      }
}

// ---------------------------------------------------------------------------
// Flash attention (causal), swapped-operand 32x32 MFMA, P in registers.
// 256 threads = 4 waves, QBLK = 128 (wave w owns q rows qb*128+w*32 ..+32).
// exp2-domain softmax; all cross-half exchanges via verified shfl_xor.
__global__ __launch_bounds__(256) void attn_kernel(const u16* __restrict__ Q,
                                                   const u16* __restrict__ K,
                                                   const u16* __restrict__ Vt,
                                                   u16* __restrict__ out) {
  __shared__ __align__(16) u16 lK[2][64 * 64];
  __shared__ __align__(16) u16 lV[2][64 * 64];
  const int tid = threadIdx.x, l = tid & 63, w = tid >> 6;
  const int n = blockIdx.x;
  // XCD grouping (n&7) + LPT: heavy qb first; pairs sum to constant work.
  const int xcd = n & 7, j = n >> 3;
  const int bh = xcd * 4 + (j & 3);   // 0..31
  const int ji = j >> 2;              // 0..15
  const int qb = (ji < 8) ? (15 - ji) : (ji - 8);
  const int b = bh >> 4, h = bh & 15;
  const int lq = l & 31, hl = l >> 5;
  const int q0w = qb * 128 + w * 32;
  const int qg = q0w + lq;  // this lane's global q row

  const u16* qbase = Q + ((((size_t)bh) << 11) + qg) * 64 + hl * 8;
  bf16x8 qf[4];
#pragma unroll
  for (int kd = 0; kd < 4; ++kd) qf[kd] = *(const bf16x8*)(qbase + kd * 16);

  const f32x16 z16 = {0.f, 0.f, 0.f, 0.f, 0.f, 0.f, 0.f, 0.f,
                      0.f, 0.f, 0.f, 0.f, 0.f, 0.f, 0.f, 0.f};
  f32x16 oacc[2];  // O^T: rows d, col q = lq
  oacc[0] = z16; oacc[1] = z16;
  float mi = -1e30f, li = 0.f;

  const int nt = 2 * qb + 2;

  // stage K [64 kv][64 d] and Vt [64 d][64 kv] for tile `it` (4 loads/thread)
#define STAGE_KV(it_, buf_)                                                        \
  {                                                                                \
    _Pragma("unroll") for (int r = 0; r < 2; ++r) {                                \
      int ch = r * 256 + tid;                                                      \
      int row = ch >> 3, s = ch & 7;                                               \
      gload_lds16(                                                                 \
          K + ((((size_t)bh) << 11) + (it_) * 64 + row) * 64 + ((s ^ (row & 7)) << 3), \
          &lK[buf_][0] + ch * 8);                                                  \
    }                                                                              \
    _Pragma("unroll") for (int r = 0; r < 2; ++r) {                                \
      int ch = r * 256 + tid;                                                      \
      int row = ch >> 3, s = ch & 7;                                               \
      gload_lds16(                                                                 \
          Vt + ((((size_t)bh) * 64 + row) << 11) + (it_) * 64 + ((s ^ (row & 7)) << 3), \
          &lV[buf_][0] + ch * 8);                                                  \
    }                                                                              \
  }

  STAGE_KV(0, 0);  // prologue: tile 0 in flight
  int cur = 0;

  for (int it = 0; it < nt; ++it) {
    const int kv0 = it * 64;
    if (it + 1 < nt) {
      STAGE_KV(it + 1, cur ^ 1);
      asm volatile("s_waitcnt vmcnt(4)" ::: "memory");  // tile it landed
    } else {
      asm volatile("s_waitcnt vmcnt(0)" ::: "memory");
    }
    __builtin_amdgcn_s_barrier();

    // waves whose q rows are all below this kv tile skip compute (still sync)
    const bool active = (kv0 <= q0w + 31);
    if (active) {
      const u16* pK = &lK[cur][0];
      const u16* pV = &lV[cur][0];

      // ---- S^T = K Q^T : sacc[g] rows = kv (32g..), cols = q ----
      f32x16 sacc[2];
      sacc[0] = z16; sacc[1] = z16;
#pragma unroll
      for (int g = 0; g < 2; ++g) {
        int row = g * 32 + lq;
        int sw = row & 7;
#pragma unroll
        for (int kd = 0; kd < 4; ++kd) {
          bf16x8 kf = *(const bf16x8*)(pK + row * 64 + (((kd * 2 + hl) ^ sw) << 3));
          sacc[g] = __builtin_amdgcn_mfma_f32_32x32x16_bf16(kf, qf[kd], sacc[g], 0, 0, 0);
        }
      }

      // ---- causal mask (only near-diagonal tiles trigger) ----
      if (kv0 + 63 > q0w) {
#pragma unroll
        for (int g = 0; g < 2; ++g)
#pragma unroll
          for (int r = 0; r < 16; ++r) {
            int kv = kv0 + g * 32 + (r & 3) + ((r >> 2) << 3) + hl * 4;
            if (kv > qg) sacc[g][r] = -1e30f;
          }
      }

      // ---- online softmax (exp2 domain; cross-half via shfl_xor) ----
      float mx[16];
#pragma unroll
      for (int r = 0; r < 16; ++r) mx[r] = fmaxf(sacc[0][r], sacc[1][r]);
#pragma unroll
      for (int s = 8; s > 0; s >>= 1)
#pragma unroll
        for (int r = 0; r < s; ++r) mx[r] = fmaxf(mx[r], mx[r + s]);
      float mt = fmaxf(mx[0], __shfl_xor(mx[0], 32, 64));

      // defer-max: skip rescale while max grows < 8 (values bounded by 2^8)
      if (!__all(mt <= mi + 8.0f)) {
        float mn = fmaxf(mi, mt);
        float al = EXP2(mi - mn);
        mi = mn;
#pragma unroll
        for (int dblk = 0; dblk < 2; ++dblk)
#pragma unroll
          for (int r = 0; r < 16; ++r) oacc[dblk][r] *= al;
        li *= al;
      }
#pragma unroll
      for (int g = 0; g < 2; ++g)
#pragma unroll
        for (int r = 0; r < 16; ++r) sacc[g][r] = EXP2(sacc[g][r] - mi);
      float sm[16];
#pragma unroll
      for (int r = 0; r < 16; ++r) sm[r] = sacc[0][r] + sacc[1][r];
#pragma unroll
      for (int s = 8; s > 0; s >>= 1)
#pragma unroll
        for (int r = 0; r < s; ++r) sm[r] += sm[r + s];
      float rs = sm[0] + __shfl_xor(sm[0], 32, 64);
      li += rs;

      // ---- P -> bf16 pairs; PV B-fragments via VERIFIED shfl_xor hl-mux ----
      u32 pw[2][8], px[2][8];
#pragma unroll
      for (int g = 0; g < 2; ++g)
#pragma unroll
        for (int i = 0; i < 8; ++i) {
          union { bf16_t h2[2]; u32 u; } pk;
          pk.h2[0] = (bf16_t)sacc[g][2 * i];
          pk.h2[1] = (bf16_t)sacc[g][2 * i + 1];
          pw[g][i] = pk.u;
        }
#pragma unroll
      for (int g = 0; g < 2; ++g)
#pragma unroll
        for (int i = 0; i < 8; ++i)
          px[g][i] = (u32)__shfl_xor((int)pw[g][i], 32, 64);

      bf16x8 pfrag[4];  // B-frag for kv chunk km*16: col=q, k=kv (hl*8+j)
#pragma unroll
      for (int km = 0; km < 4; ++km) {
        const int g = km >> 1, o = (km & 1) * 4;
        union { u32 u[4]; bf16x8 v; } f;
        f.u[0] = hl ? px[g][o + 2] : pw[g][o + 0];
        f.u[1] = hl ? px[g][o + 3] : pw[g][o + 1];
        f.u[2] = hl ? pw[g][o + 2] : px[g][o + 0];
        f.u[3] = hl ? pw[g][o + 3] : px[g][o + 1];
        pfrag[km] = f.v;
      }

      // ---- O^T += V^T P^T ----
#pragma unroll
      for (int dblk = 0; dblk < 2; ++dblk) {
        int row = dblk * 32 + lq;
        int sw = row & 7;
#pragma unroll
        for (int km = 0; km < 4; ++km) {
          bf16x8 vf = *(const bf16x8*)(pV + row * 64 + (((km * 2 + hl) ^ sw) << 3));
          oacc[dblk] = __builtin_amdgcn_mfma_f32_32x32x16_bf16(vf, pfrag[km],
                                                              oacc[dblk], 0, 0, 0);
        }
      }
    }
    __builtin_amdgcn_s_barrier();  // all waves done reading buf cur
    cur ^= 1;
  }
#undef STAGE_KV

  // ---- write O^T / li to At[B,T,C] (bf16) ----
  const float inv = 1.0f / li;
  const size_t rowbase = ((size_t)(b * 2048 + qg)) * 1024 + h * 64;
#pragma unroll
  for (int dblk = 0; dblk < 2; ++dblk)
#pragma unroll
    for (int grp = 0; grp < 4; ++grp) {
      ushort4 st;
      st.x = f2bf(oacc[dblk][grp * 4 + 0] * inv);
      st.y = f2bf(oacc[dblk][grp * 4 + 1] * inv);
      st.z = f2bf(oacc[dblk][grp * 4 + 2] * inv);
      st.w = f2bf(oacc[dblk][grp * 4 + 3] * inv);
      *(ushort4*)((u16*)out + rowbase + dblk * 32 + grp * 8 + hl * 4) = st;
    }
}

// ---------------------------------------------------------------------------
__global__ __launch_bounds__(256) void outproj_kernel(const u16* __restrict__ attn,
                                                      const u16* __restrict__ Wob,
                                                      const float* __restrict__ bo,
                                                      float* __restrict__ out) {
  __shared__ __align__(16) u16 lA[2 * 128 * 64];
  __shared__ __align__(16) u16 lB[2 * 128 * 64];
  const int m0 = blockIdx.y * 128, n0 = blockIdx.x * 128;
  f32x4 acc[4][4];
  gemm_tile_db(attn, Wob, m0, n0, lA, lB, acc);
  const int tid = threadIdx.x, l = tid & 63;
  const int wr = tid >> 7, wc = (tid >> 6) & 1;
#pragma unroll
  for (int m = 0; m < 4; ++m)
#pragma unroll
    for (int n = 0; n < 4; ++n)
#pragma unroll
      for (int jr = 0; jr < 4; ++jr) {
        int gr = m0 + wr * 64 + m * 16 + ((l >> 4) << 2) + jr;
        int gc = n0 + wc * 64 + n * 16 + (l & 15);
        out[(size_t)gr * 1024 + gc] = acc[m][n][jr] + bo[gc];
      }
}

// ---------------------------------------------------------------------------
extern "C" void kernel_launch(void* const* d_in, const int* in_sizes, int n_in,
                              void* d_out, int out_size, void* d_ws, size_t ws_size,
                              hipStream_t stream) {
  const float* x  = (const float*)d_in[0];
  const float* Wq = (const float*)d_in[1];
  const float* bq = (const float*)d_in[2];
  const float* Wk = (const float*)d_in[3];
  const float* bk = (const float*)d_in[4];
  const float* Wv = (const float*)d_in[5];
  const float* bv = (const float*)d_in[6];
  const float* Wo = (const float*)d_in[7];
  const float* bo = (const float*)d_in[8];
  float* out = (float*)d_out;

  char* ws = (char*)d_ws;
  u16* xb  = (u16*)(ws);                          // 8 MB
  u16* Wqb = (u16*)(ws + (8ull << 20));           // 2 MB
  u16* Wkb = (u16*)(ws + (10ull << 20));          // 2 MB
  u16* Wvb = (u16*)(ws + (12ull << 20));          // 2 MB
  u16* Wob = (u16*)(ws + (14ull << 20));          // 2 MB
  u16* Qr  = (u16*)(ws + (16ull << 20));          // 8 MB  [B,H,T,D] (pre-scaled)
  u16* Kr  = (u16*)(ws + (24ull << 20));          // 8 MB  [B,H,T,D]
  u16* Vt  = (u16*)(ws + (32ull << 20));          // 8 MB  [B,H,D,T]
  u16* At  = (u16*)(ws + (40ull << 20));          // 8 MB  attn out bf16 [B,T,C]
  float* tab = (float*)(ws + (48ull << 20));      // 512 KB rope table

  cvt_kernel<<<dim3(4096), dim3(256), 0, stream>>>(x, xb, 1048576);
  cvtw_kernel<<<dim3(1024, 4), dim3(256), 0, stream>>>(Wq, Wk, Wv, Wo,
                                                       Wqb, Wkb, Wvb, Wob);
  rope_table_kernel<<<dim3(256), dim3(256), 0, stream>>>(tab);

  qkv_kernel<<<dim3(8, 32, 3), dim3(256), 0, stream>>>(xb, Wqb, Wkb, Wvb, bq, bk, bv,
                                                       tab, Qr, Kr, Vt);
  attn_kernel<<<dim3(512), dim3(256), 0, stream>>>(Qr, Kr, Vt, At);
  outproj_kernel<<<dim3(8, 32), dim3(256), 0, stream>>>(At, Wob, bo, out);
}

// Round 8
// 141.408 us; speedup vs baseline: 1.3465x; 1.1683x over previous
//
#include <hip/hip_runtime.h>

// ---------------------------------------------------------------------------
// TrajectoryAttention: x@Wq.T+bq / Wk / Wv -> RoPE(q,k) -> causal attn -> @Wo.T+bo
// B=2, T=2048, C=1024, H=16, D=64.  All matmuls bf16 MFMA (fp32 accum).
// R8: GEMMs go 256x256 tile / 8 waves (wave tile 128x64: FLOP/LDS-byte 64->87,
//     LDS pipe no longer over MFMA), same counted-vmcnt(8) 2-phase structure.
//     QKV fused into one N=3072 GEMM; LDS-transpose epilogue (coalesced bf16x8
//     stores, V scatter eliminated); all prep fused into one launch.
// ---------------------------------------------------------------------------

typedef unsigned short u16;
typedef unsigned int u32;
typedef __bf16 bf16_t;
typedef bf16_t bf16x8 __attribute__((ext_vector_type(8)));
typedef float f32x4 __attribute__((ext_vector_type(4)));
typedef float f32x16 __attribute__((ext_vector_type(16)));

#if __has_builtin(__builtin_amdgcn_exp2f)
#define EXP2(x) __builtin_amdgcn_exp2f(x)
#else
#define EXP2(x) exp2f(x)
#endif

__device__ __forceinline__ u16 f2bf(float f) {
  union { float f; unsigned u; } v; v.f = f;
  return (u16)((v.u + 0x7FFFu + ((v.u >> 16) & 1u)) >> 16);  // RNE
}

__device__ __forceinline__ void gload_lds16(const void* g, void* l) {
  __builtin_amdgcn_global_load_lds(
      (const __attribute__((address_space(1))) void*)g,
      (__attribute__((address_space(3))) void*)l, 16, 0, 0);
}

// ---------------------------------------------------------------------------
// Fused prep: x->bf16, 4 weights->bf16 (into contiguous region), rope table,
// bias concat.  One launch, 8460 blocks.
__global__ __launch_bounds__(256) void prep_kernel(
    const float* __restrict__ x, const float* __restrict__ Wq,
    const float* __restrict__ Wk, const float* __restrict__ Wv,
    const float* __restrict__ Wo, const float* __restrict__ bq,
    const float* __restrict__ bk, const float* __restrict__ bv,
    u16* __restrict__ xb, u16* __restrict__ Wqkvo, float* __restrict__ tab,
    float* __restrict__ bcat) {
  const int bid = blockIdx.x, tid = threadIdx.x;
  if (bid < 4096) {  // x: 1048576 float4
    int i = bid * 256 + tid;
    float4 f = ((const float4*)x)[i];
    ushort4 o;
    o.x = f2bf(f.x); o.y = f2bf(f.y); o.z = f2bf(f.z); o.w = f2bf(f.w);
    ((ushort4*)xb)[i] = o;
  } else if (bid < 8192) {  // weights: 4 x 262144 float4 -> contiguous bf16
    int wsel = (bid - 4096) >> 10;
    int i = ((bid - 4096) & 1023) * 256 + tid;
    const float* in = (wsel == 0) ? Wq : (wsel == 1) ? Wk : (wsel == 2) ? Wv : Wo;
    float4 f = ((const float4*)in)[i];
    ushort4 o;
    o.x = f2bf(f.x); o.y = f2bf(f.y); o.z = f2bf(f.z); o.w = f2bf(f.w);
    ((ushort4*)(Wqkvo + (size_t)wsel * 1048576))[i] = o;
  } else if (bid < 8448) {  // rope table: T*32 = 65536
    int idx = (bid - 8192) * 256 + tid;
    int t = idx >> 5, i = idx & 31;
    float freq = powf(10000.0f, -(float)i * (1.0f / 32.0f));
    float a = (float)t * freq;
    tab[t * 64 + i] = cosf(a);
    tab[t * 64 + 32 + i] = sinf(a);
  } else {  // bias concat: 3072 floats
    int j = (bid - 8448) * 256 + tid;
    float v = (j < 1024) ? bq[j] : (j < 2048) ? bk[j - 1024] : bv[j - 2048];
    bcat[j] = v;
  }
}

// ---------------------------------------------------------------------------
// Stage one 256x64 A-tile + 256x64 B-tile into LDS (8 gload_lds / thread,
// 512 threads).  Slot-swizzled source so swizzled ds_read_b128 is bank-clean.
__device__ __forceinline__ void stage256(const u16* __restrict__ A,
                                         const u16* __restrict__ Bt,
                                         int m0, int n0, int k0,
                                         u16* lA, u16* lB, int tid) {
#pragma unroll
  for (int r = 0; r < 4; ++r) {
    int ch = r * 512 + tid;  // 2048 chunks of 16B
    int row = ch >> 3, s = ch & 7;
    gload_lds16(A + (size_t)(m0 + row) * 1024 + k0 + ((s ^ (row & 7)) << 3),
                lA + ch * 8);
  }
#pragma unroll
  for (int r = 0; r < 4; ++r) {
    int ch = r * 512 + tid;
    int row = ch >> 3, s = ch & 7;
    gload_lds16(Bt + (size_t)(n0 + row) * 1024 + k0 + ((s ^ (row & 7)) << 3),
                lB + ch * 8);
  }
}

// 256x256 double-buffered GEMM mainloop, counted vmcnt (verified structure):
//   stage(t+1); s_waitcnt vmcnt(8); s_barrier; compute(t); s_barrier
// 8 waves (2M x 4N), wave tile 128x64, K=1024 (16 steps of BK=64).
__device__ __forceinline__ void gemm256_db(const u16* __restrict__ A,
                                           const u16* __restrict__ Bt,
                                           int m0, int n0, u16* lA, u16* lB,
                                           f32x4 acc[8][4]) {
  const int tid = threadIdx.x;
  const int l = tid & 63;
  const int wid = tid >> 6, wr = wid >> 2, wc = wid & 3;

#pragma unroll
  for (int m = 0; m < 8; ++m)
#pragma unroll
    for (int n = 0; n < 4; ++n)
      acc[m][n] = (f32x4){0.f, 0.f, 0.f, 0.f};

  stage256(A, Bt, m0, n0, 0, lA, lB, tid);  // prologue: tile 0 in flight

  int cur = 0;
  for (int t = 0; t < 16; ++t) {
    if (t + 1 < 16) {
      stage256(A, Bt, m0, n0, (t + 1) * 64, lA + (cur ^ 1) * 16384,
               lB + (cur ^ 1) * 16384, tid);
      asm volatile("s_waitcnt vmcnt(8)" ::: "memory");  // tile t landed
    } else {
      asm volatile("s_waitcnt vmcnt(0)" ::: "memory");
    }
    __builtin_amdgcn_s_barrier();

    const u16* pA = lA + cur * 16384;
    const u16* pB = lB + cur * 16384;
#pragma unroll
    for (int kk = 0; kk < 2; ++kk) {
      bf16x8 af[8], bf[4];
#pragma unroll
      for (int m = 0; m < 8; ++m) {
        int row = wr * 128 + m * 16 + (l & 15);
        int slot = (kk * 4 + (l >> 4)) ^ (row & 7);
        af[m] = *(const bf16x8*)(pA + row * 64 + slot * 8);
      }
#pragma unroll
      for (int n = 0; n < 4; ++n) {
        int row = wc * 64 + n * 16 + (l & 15);
        int slot = (kk * 4 + (l >> 4)) ^ (row & 7);
        bf[n] = *(const bf16x8*)(pB + row * 64 + slot * 8);
      }
#pragma unroll
      for (int m = 0; m < 8; ++m)
#pragma unroll
        for (int n = 0; n < 4; ++n)
          acc[m][n] =
              __builtin_amdgcn_mfma_f32_16x16x32_bf16(af[m], bf[n], acc[m][n], 0, 0, 0);
    }
    __builtin_amdgcn_s_barrier();
    cur ^= 1;
  }
}

// ---------------------------------------------------------------------------
// Fused QKV projection (N=3072) + bias + RoPE + LDS-transpose epilogue.
// Each wave's 128x64 output sub-tile is exactly one (z,h) panel x 128 tokens.
__global__ __launch_bounds__(512, 2) void qkv_kernel(
    const u16* __restrict__ xb, const u16* __restrict__ Wqkv,
    const float* __restrict__ bcat, const float* __restrict__ tab,
    u16* __restrict__ Q, u16* __restrict__ Kr, u16* __restrict__ Vt) {
  __shared__ __align__(16) u16 lds[65536];  // 128 KB: staging, then epilogue
  const int m0 = blockIdx.y * 256, n0 = blockIdx.x * 256;

  f32x4 acc[8][4];
  gemm256_db(xb, Wqkv, m0, n0, lds, lds + 32768, acc);

  const int tid = threadIdx.x, l = tid & 63;
  const int wid = tid >> 6, wr = wid >> 2, wc = wid & 3;
  const int gcb = n0 + wc * 64;        // wave col base (mult of 64)
  const int z = gcb >> 10, h = (gcb >> 6) & 15;
  const int grb = m0 + wr * 128;       // wave row base (mult of 128)
  const int b2 = grb >> 11, t0 = grb & 2047;
  u16* myl = lds + wid * 8192;         // 16 KB per-wave epilogue region

  if (z < 2) {
    // Q/K: RoPE in-register, LDS layout [tl][d] == global layout (linear)
#pragma unroll
    for (int m = 0; m < 8; ++m)
#pragma unroll
      for (int n = 0; n < 4; ++n)
#pragma unroll
        for (int jr = 0; jr < 4; ++jr) {
          int tl = m * 16 + ((l >> 4) << 2) + jr;
          int d = n * 16 + (l & 15);
          int t = t0 + tl;
          float val = acc[m][n][jr] + bcat[gcb + d];
          float p = acc[m][n ^ 2][jr] + bcat[gcb + (d ^ 32)];
          float cs = tab[t * 64 + (d & 31)];
          float sn = tab[t * 64 + 32 + (d & 31)];
          float rot = (d < 32) ? -p : p;
          float o = val * cs + rot * sn;
          if (z == 0) o *= 0.18033688011112042f;  // 1/sqrt(64) * log2(e)
          myl[tl * 64 + d] = f2bf(o);
        }
    asm volatile("s_waitcnt lgkmcnt(0)" ::: "memory");
    u16* dstb = ((z == 0) ? Q : Kr) + (((size_t)(b2 * 16 + h) << 11) + t0) * 64;
#pragma unroll
    for (int i = 0; i < 16; ++i) {
      int c = i * 64 + l;
      *(bf16x8*)(dstb + c * 8) = *(const bf16x8*)(myl + c * 8);
    }
  } else {
    // V: LDS [d][tl] (XOR-swizzled to spread d across banks), store V^T rows
#pragma unroll
    for (int m = 0; m < 8; ++m)
#pragma unroll
      for (int n = 0; n < 4; ++n)
#pragma unroll
        for (int jr = 0; jr < 4; ++jr) {
          int tl = m * 16 + ((l >> 4) << 2) + jr;
          int d = n * 16 + (l & 15);
          float val = acc[m][n][jr] + bcat[gcb + d];
          myl[d * 128 + (tl ^ ((d & 7) << 4))] = f2bf(val);
        }
    asm volatile("s_waitcnt lgkmcnt(0)" ::: "memory");
#pragma unroll
    for (int i = 0; i < 16; ++i) {
      int c = i * 64 + l;
      int d = c >> 4, off = (c & 15) * 8;
      bf16x8 v = *(const bf16x8*)(myl + d * 128 + (off ^ ((d & 7) << 4)));
      *(bf16x8*)(Vt + (((size_t)((b2 * 16 + h) * 64 + d)) << 11) + t0 + off) = v;
    }
  }
}

// ---------------------------------------------------------------------------
// Output projection on the same 256x256 routine; fp32 stores (coalesced).
__global__ __launch_bounds__(512, 2) void outproj_kernel(
    const u16* __restrict__ attn, const u16* __restrict__ Wob,
    const float* __restrict__ bo, float* __restrict__ out) {
  __shared__ __align__(16) u16 lds[65536];
  const int m0 = blockIdx.y * 256, n0 = blockIdx.x * 256;
  f32x4 acc[8][4];
  gemm256_db(attn, Wob, m0, n0, lds, lds + 32768, acc);
  const int tid = threadIdx.x, l = tid & 63;
  const int wid = tid >> 6, wr = wid >> 2, wc = wid & 3;
#pragma unroll
  for (int m = 0; m < 8; ++m)
#pragma unroll
    for (int n = 0; n < 4; ++n)
#pragma unroll
      for (int jr = 0; jr < 4; ++jr) {
        int gr = m0 + wr * 128 + m * 16 + ((l >> 4) << 2) + jr;
        int gc = n0 + wc * 64 + n * 16 + (l & 15);
        out[(size_t)gr * 1024 + gc] = acc[m][n][jr] + bo[gc];
      }
}

// ---------------------------------------------------------------------------
// Flash attention (causal) — unchanged from verified R7.
__global__ __launch_bounds__(256) void attn_kernel(const u16* __restrict__ Q,
                                                   const u16* __restrict__ K,
                                                   const u16* __restrict__ Vt,
                                                   u16* __restrict__ out) {
  __shared__ __align__(16) u16 lK[2][64 * 64];
  __shared__ __align__(16) u16 lV[2][64 * 64];
  const int tid = threadIdx.x, l = tid & 63, w = tid >> 6;
  const int n = blockIdx.x;
  const int xcd = n & 7, j = n >> 3;
  const int bh = xcd * 4 + (j & 3);   // 0..31
  const int ji = j >> 2;              // 0..15
  const int qb = (ji < 8) ? (15 - ji) : (ji - 8);
  const int b = bh >> 4, h = bh & 15;
  const int lq = l & 31, hl = l >> 5;
  const int q0w = qb * 128 + w * 32;
  const int qg = q0w + lq;

  const u16* qbase = Q + ((((size_t)bh) << 11) + qg) * 64 + hl * 8;
  bf16x8 qf[4];
#pragma unroll
  for (int kd = 0; kd < 4; ++kd) qf[kd] = *(const bf16x8*)(qbase + kd * 16);

  const f32x16 z16 = {0.f, 0.f, 0.f, 0.f, 0.f, 0.f, 0.f, 0.f,
                      0.f, 0.f, 0.f, 0.f, 0.f, 0.f, 0.f, 0.f};
  f32x16 oacc[2];
  oacc[0] = z16; oacc[1] = z16;
  float mi = -1e30f, li = 0.f;

  const int nt = 2 * qb + 2;

#define STAGE_KV(it_, buf_)                                                        \
  {                                                                                \
    _Pragma("unroll") for (int r = 0; r < 2; ++r) {                                \
      int ch = r * 256 + tid;                                                      \
      int row = ch >> 3, s = ch & 7;                                               \
      gload_lds16(                                                                 \
          K + ((((size_t)bh) << 11) + (it_) * 64 + row) * 64 + ((s ^ (row & 7)) << 3), \
          &lK[buf_][0] + ch * 8);                                                  \
    }                                                                              \
    _Pragma("unroll") for (int r = 0; r < 2; ++r) {                                \
      int ch = r * 256 + tid;                                                      \
      int row = ch >> 3, s = ch & 7;                                               \
      gload_lds16(                                                                 \
          Vt + ((((size_t)bh) * 64 + row) << 11) + (it_) * 64 + ((s ^ (row & 7)) << 3), \
          &lV[buf_][0] + ch * 8);                                                  \
    }                                                                              \
  }

  STAGE_KV(0, 0);
  int cur = 0;

  for (int it = 0; it < nt; ++it) {
    const int kv0 = it * 64;
    if (it + 1 < nt) {
      STAGE_KV(it + 1, cur ^ 1);
      asm volatile("s_waitcnt vmcnt(4)" ::: "memory");
    } else {
      asm volatile("s_waitcnt vmcnt(0)" ::: "memory");
    }
    __builtin_amdgcn_s_barrier();

    const bool active = (kv0 <= q0w + 31);
    if (active) {
      const u16* pK = &lK[cur][0];
      const u16* pV = &lV[cur][0];

      f32x16 sacc[2];
      sacc[0] = z16; sacc[1] = z16;
#pragma unroll
      for (int g = 0; g < 2; ++g) {
        int row = g * 32 + lq;
        int sw = row & 7;
#pragma unroll
        for (int kd = 0; kd < 4; ++kd) {
          bf16x8 kf = *(const bf16x8*)(pK + row * 64 + (((kd * 2 + hl) ^ sw) << 3));
          sacc[g] = __builtin_amdgcn_mfma_f32_32x32x16_bf16(kf, qf[kd], sacc[g], 0, 0, 0);
        }
      }

      if (kv0 + 63 > q0w) {
#pragma unroll
        for (int g = 0; g < 2; ++g)
#pragma unroll
          for (int r = 0; r < 16; ++r) {
            int kv = kv0 + g * 32 + (r & 3) + ((r >> 2) << 3) + hl * 4;
            if (kv > qg) sacc[g][r] = -1e30f;
          }
      }

      float mx[16];
#pragma unroll
      for (int r = 0; r < 16; ++r) mx[r] = fmaxf(sacc[0][r], sacc[1][r]);
#pragma unroll
      for (int s = 8; s > 0; s >>= 1)
#pragma unroll
        for (int r = 0; r < s; ++r) mx[r] = fmaxf(mx[r], mx[r + s]);
      float mt = fmaxf(mx[0], __shfl_xor(mx[0], 32, 64));

      if (!__all(mt <= mi + 8.0f)) {
        float mn = fmaxf(mi, mt);
        float al = EXP2(mi - mn);
        mi = mn;
#pragma unroll
        for (int dblk = 0; dblk < 2; ++dblk)
#pragma unroll
          for (int r = 0; r < 16; ++r) oacc[dblk][r] *= al;
        li *= al;
      }
#pragma unroll
      for (int g = 0; g < 2; ++g)
#pragma unroll
        for (int r = 0; r < 16; ++r) sacc[g][r] = EXP2(sacc[g][r] - mi);
      float sm[16];
#pragma unroll
      for (int r = 0; r < 16; ++r) sm[r] = sacc[0][r] + sacc[1][r];
#pragma unroll
      for (int s = 8; s > 0; s >>= 1)
#pragma unroll
        for (int r = 0; r < s; ++r) sm[r] += sm[r + s];
      float rs = sm[0] + __shfl_xor(sm[0], 32, 64);
      li += rs;

      u32 pw[2][8], px[2][8];
#pragma unroll
      for (int g = 0; g < 2; ++g)
#pragma unroll
        for (int i = 0; i < 8; ++i) {
          union { bf16_t h2[2]; u32 u; } pk;
          pk.h2[0] = (bf16_t)sacc[g][2 * i];
          pk.h2[1] = (bf16_t)sacc[g][2 * i + 1];
          pw[g][i] = pk.u;
        }
#pragma unroll
      for (int g = 0; g < 2; ++g)
#pragma unroll
        for (int i = 0; i < 8; ++i)
          px[g][i] = (u32)__shfl_xor((int)pw[g][i], 32, 64);

      bf16x8 pfrag[4];
#pragma unroll
      for (int km = 0; km < 4; ++km) {
        const int g = km >> 1, o = (km & 1) * 4;
        union { u32 u[4]; bf16x8 v; } f;
        f.u[0] = hl ? px[g][o + 2] : pw[g][o + 0];
        f.u[1] = hl ? px[g][o + 3] : pw[g][o + 1];
        f.u[2] = hl ? pw[g][o + 2] : px[g][o + 0];
        f.u[3] = hl ? pw[g][o + 3] : px[g][o + 1];
        pfrag[km] = f.v;
      }

#pragma unroll
      for (int dblk = 0; dblk < 2; ++dblk) {
        int row = dblk * 32 + lq;
        int sw = row & 7;
#pragma unroll
        for (int km = 0; km < 4; ++km) {
          bf16x8 vf = *(const bf16x8*)(pV + row * 64 + (((km * 2 + hl) ^ sw) << 3));
          oacc[dblk] = __builtin_amdgcn_mfma_f32_32x32x16_bf16(vf, pfrag[km],
                                                              oacc[dblk], 0, 0, 0);
        }
      }
    }
    __builtin_amdgcn_s_barrier();
    cur ^= 1;
  }
#undef STAGE_KV

  const float inv = 1.0f / li;
  const size_t rowbase = ((size_t)(b * 2048 + qg)) * 1024 + h * 64;
#pragma unroll
  for (int dblk = 0; dblk < 2; ++dblk)
#pragma unroll
    for (int grp = 0; grp < 4; ++grp) {
      ushort4 st;
      st.x = f2bf(oacc[dblk][grp * 4 + 0] * inv);
      st.y = f2bf(oacc[dblk][grp * 4 + 1] * inv);
      st.z = f2bf(oacc[dblk][grp * 4 + 2] * inv);
      st.w = f2bf(oacc[dblk][grp * 4 + 3] * inv);
      *(ushort4*)((u16*)out + rowbase + dblk * 32 + grp * 8 + hl * 4) = st;
    }
}

// ---------------------------------------------------------------------------
extern "C" void kernel_launch(void* const* d_in, const int* in_sizes, int n_in,
                              void* d_out, int out_size, void* d_ws, size_t ws_size,
                              hipStream_t stream) {
  const float* x  = (const float*)d_in[0];
  const float* Wq = (const float*)d_in[1];
  const float* bq = (const float*)d_in[2];
  const float* Wk = (const float*)d_in[3];
  const float* bk = (const float*)d_in[4];
  const float* Wv = (const float*)d_in[5];
  const float* bv = (const float*)d_in[6];
  const float* Wo = (const float*)d_in[7];
  const float* bo = (const float*)d_in[8];
  float* out = (float*)d_out;

  char* ws = (char*)d_ws;
  u16* xb    = (u16*)(ws);                        // 8 MB
  u16* Wqkvo = (u16*)(ws + (8ull << 20));         // 8 MB: Wq|Wk|Wv|Wo contiguous
  u16* Wob   = Wqkvo + 3 * 1048576;
  u16* Qr  = (u16*)(ws + (16ull << 20));          // 8 MB  [B,H,T,D] (pre-scaled)
  u16* Kr  = (u16*)(ws + (24ull << 20));          // 8 MB  [B,H,T,D]
  u16* Vt  = (u16*)(ws + (32ull << 20));          // 8 MB  [B,H,D,T]
  u16* At  = (u16*)(ws + (40ull << 20));          // 8 MB  attn out bf16 [B,T,C]
  float* tab  = (float*)(ws + (48ull << 20));     // 512 KB rope table
  float* bcat = (float*)(ws + (48ull << 20) + (512ull << 10));  // 12 KB

  prep_kernel<<<dim3(8460), dim3(256), 0, stream>>>(x, Wq, Wk, Wv, Wo, bq, bk, bv,
                                                    xb, Wqkvo, tab, bcat);
  qkv_kernel<<<dim3(12, 16), dim3(512), 0, stream>>>(xb, Wqkvo, bcat, tab,
                                                     Qr, Kr, Vt);
  attn_kernel<<<dim3(512), dim3(256), 0, stream>>>(Qr, Kr, Vt, At);
  outproj_kernel<<<dim3(4, 16), dim3(512), 0, stream>>>(At, Wob, bo, out);
}

// Round 9
// 129.819 us; speedup vs baseline: 1.4667x; 1.0893x over previous
//
#include <hip/hip_runtime.h>

// ---------------------------------------------------------------------------
// TrajectoryAttention: x@Wq.T+bq / Wk / Wv -> RoPE(q,k) -> causal attn -> @Wo.T+bo
// B=2, T=2048, C=1024, H=16, D=64.  All matmuls bf16 MFMA (fp32 accum).
// R9: attn: 8-wave blocks, in-block KV-SPLIT (waves 0-3 kv half A, waves 4-7
//     kv half B, same q rows), LDS online-softmax merge at block end.
//     16 waves/CU (4/SIMD) and sequential depth 2qb+2 -> qb+1.
//     GEMMs (256x256 counted-vmcnt) and prep unchanged from R8.
// ---------------------------------------------------------------------------

typedef unsigned short u16;
typedef unsigned int u32;
typedef __bf16 bf16_t;
typedef bf16_t bf16x8 __attribute__((ext_vector_type(8)));
typedef float f32x4 __attribute__((ext_vector_type(4)));
typedef float f32x16 __attribute__((ext_vector_type(16)));

#if __has_builtin(__builtin_amdgcn_exp2f)
#define EXP2(x) __builtin_amdgcn_exp2f(x)
#else
#define EXP2(x) exp2f(x)
#endif

__device__ __forceinline__ u16 f2bf(float f) {
  union { float f; unsigned u; } v; v.f = f;
  return (u16)((v.u + 0x7FFFu + ((v.u >> 16) & 1u)) >> 16);  // RNE
}

__device__ __forceinline__ void gload_lds16(const void* g, void* l) {
  __builtin_amdgcn_global_load_lds(
      (const __attribute__((address_space(1))) void*)g,
      (__attribute__((address_space(3))) void*)l, 16, 0, 0);
}

// ---------------------------------------------------------------------------
// Fused prep: x->bf16, 4 weights->bf16 (contiguous), rope table, bias concat.
__global__ __launch_bounds__(256) void prep_kernel(
    const float* __restrict__ x, const float* __restrict__ Wq,
    const float* __restrict__ Wk, const float* __restrict__ Wv,
    const float* __restrict__ Wo, const float* __restrict__ bq,
    const float* __restrict__ bk, const float* __restrict__ bv,
    u16* __restrict__ xb, u16* __restrict__ Wqkvo, float* __restrict__ tab,
    float* __restrict__ bcat) {
  const int bid = blockIdx.x, tid = threadIdx.x;
  if (bid < 4096) {  // x: 1048576 float4
    int i = bid * 256 + tid;
    float4 f = ((const float4*)x)[i];
    ushort4 o;
    o.x = f2bf(f.x); o.y = f2bf(f.y); o.z = f2bf(f.z); o.w = f2bf(f.w);
    ((ushort4*)xb)[i] = o;
  } else if (bid < 8192) {  // weights: 4 x 262144 float4 -> contiguous bf16
    int wsel = (bid - 4096) >> 10;
    int i = ((bid - 4096) & 1023) * 256 + tid;
    const float* in = (wsel == 0) ? Wq : (wsel == 1) ? Wk : (wsel == 2) ? Wv : Wo;
    float4 f = ((const float4*)in)[i];
    ushort4 o;
    o.x = f2bf(f.x); o.y = f2bf(f.y); o.z = f2bf(f.z); o.w = f2bf(f.w);
    ((ushort4*)(Wqkvo + (size_t)wsel * 1048576))[i] = o;
  } else if (bid < 8448) {  // rope table: T*32 = 65536
    int idx = (bid - 8192) * 256 + tid;
    int t = idx >> 5, i = idx & 31;
    float freq = powf(10000.0f, -(float)i * (1.0f / 32.0f));
    float a = (float)t * freq;
    tab[t * 64 + i] = cosf(a);
    tab[t * 64 + 32 + i] = sinf(a);
  } else {  // bias concat: 3072 floats
    int j = (bid - 8448) * 256 + tid;
    float v = (j < 1024) ? bq[j] : (j < 2048) ? bk[j - 1024] : bv[j - 2048];
    bcat[j] = v;
  }
}

// ---------------------------------------------------------------------------
// Stage one 256x64 A-tile + 256x64 B-tile into LDS (8 gload_lds / thread).
__device__ __forceinline__ void stage256(const u16* __restrict__ A,
                                         const u16* __restrict__ Bt,
                                         int m0, int n0, int k0,
                                         u16* lA, u16* lB, int tid) {
#pragma unroll
  for (int r = 0; r < 4; ++r) {
    int ch = r * 512 + tid;  // 2048 chunks of 16B
    int row = ch >> 3, s = ch & 7;
    gload_lds16(A + (size_t)(m0 + row) * 1024 + k0 + ((s ^ (row & 7)) << 3),
                lA + ch * 8);
  }
#pragma unroll
  for (int r = 0; r < 4; ++r) {
    int ch = r * 512 + tid;
    int row = ch >> 3, s = ch & 7;
    gload_lds16(Bt + (size_t)(n0 + row) * 1024 + k0 + ((s ^ (row & 7)) << 3),
                lB + ch * 8);
  }
}

// 256x256 double-buffered GEMM mainloop, counted vmcnt (verified structure).
__device__ __forceinline__ void gemm256_db(const u16* __restrict__ A,
                                           const u16* __restrict__ Bt,
                                           int m0, int n0, u16* lA, u16* lB,
                                           f32x4 acc[8][4]) {
  const int tid = threadIdx.x;
  const int l = tid & 63;
  const int wid = tid >> 6, wr = wid >> 2, wc = wid & 3;

#pragma unroll
  for (int m = 0; m < 8; ++m)
#pragma unroll
    for (int n = 0; n < 4; ++n)
      acc[m][n] = (f32x4){0.f, 0.f, 0.f, 0.f};

  stage256(A, Bt, m0, n0, 0, lA, lB, tid);  // prologue: tile 0 in flight

  int cur = 0;
  for (int t = 0; t < 16; ++t) {
    if (t + 1 < 16) {
      stage256(A, Bt, m0, n0, (t + 1) * 64, lA + (cur ^ 1) * 16384,
               lB + (cur ^ 1) * 16384, tid);
      asm volatile("s_waitcnt vmcnt(8)" ::: "memory");  // tile t landed
    } else {
      asm volatile("s_waitcnt vmcnt(0)" ::: "memory");
    }
    __builtin_amdgcn_s_barrier();

    const u16* pA = lA + cur * 16384;
    const u16* pB = lB + cur * 16384;
#pragma unroll
    for (int kk = 0; kk < 2; ++kk) {
      bf16x8 af[8], bf[4];
#pragma unroll
      for (int m = 0; m < 8; ++m) {
        int row = wr * 128 + m * 16 + (l & 15);
        int slot = (kk * 4 + (l >> 4)) ^ (row & 7);
        af[m] = *(const bf16x8*)(pA + row * 64 + slot * 8);
      }
#pragma unroll
      for (int n = 0; n < 4; ++n) {
        int row = wc * 64 + n * 16 + (l & 15);
        int slot = (kk * 4 + (l >> 4)) ^ (row & 7);
        bf[n] = *(const bf16x8*)(pB + row * 64 + slot * 8);
      }
#pragma unroll
      for (int m = 0; m < 8; ++m)
#pragma unroll
        for (int n = 0; n < 4; ++n)
          acc[m][n] =
              __builtin_amdgcn_mfma_f32_16x16x32_bf16(af[m], bf[n], acc[m][n], 0, 0, 0);
    }
    __builtin_amdgcn_s_barrier();
    cur ^= 1;
  }
}

// ---------------------------------------------------------------------------
// Fused QKV projection (N=3072) + bias + RoPE + LDS-transpose epilogue.
__global__ __launch_bounds__(512, 2) void qkv_kernel(
    const u16* __restrict__ xb, const u16* __restrict__ Wqkv,
    const float* __restrict__ bcat, const float* __restrict__ tab,
    u16* __restrict__ Q, u16* __restrict__ Kr, u16* __restrict__ Vt) {
  __shared__ __align__(16) u16 lds[65536];  // 128 KB: staging, then epilogue
  const int m0 = blockIdx.y * 256, n0 = blockIdx.x * 256;

  f32x4 acc[8][4];
  gemm256_db(xb, Wqkv, m0, n0, lds, lds + 32768, acc);

  const int tid = threadIdx.x, l = tid & 63;
  const int wid = tid >> 6, wr = wid >> 2, wc = wid & 3;
  const int gcb = n0 + wc * 64;        // wave col base (mult of 64)
  const int z = gcb >> 10, h = (gcb >> 6) & 15;
  const int grb = m0 + wr * 128;       // wave row base (mult of 128)
  const int b2 = grb >> 11, t0 = grb & 2047;
  u16* myl = lds + wid * 8192;         // 16 KB per-wave epilogue region

  if (z < 2) {
#pragma unroll
    for (int m = 0; m < 8; ++m)
#pragma unroll
      for (int n = 0; n < 4; ++n)
#pragma unroll
        for (int jr = 0; jr < 4; ++jr) {
          int tl = m * 16 + ((l >> 4) << 2) + jr;
          int d = n * 16 + (l & 15);
          int t = t0 + tl;
          float val = acc[m][n][jr] + bcat[gcb + d];
          float p = acc[m][n ^ 2][jr] + bcat[gcb + (d ^ 32)];
          float cs = tab[t * 64 + (d & 31)];
          float sn = tab[t * 64 + 32 + (d & 31)];
          float rot = (d < 32) ? -p : p;
          float o = val * cs + rot * sn;
          if (z == 0) o *= 0.18033688011112042f;  // 1/sqrt(64) * log2(e)
          myl[tl * 64 + d] = f2bf(o);
        }
    asm volatile("s_waitcnt lgkmcnt(0)" ::: "memory");
    u16* dstb = ((z == 0) ? Q : Kr) + (((size_t)(b2 * 16 + h) << 11) + t0) * 64;
#pragma unroll
    for (int i = 0; i < 16; ++i) {
      int c = i * 64 + l;
      *(bf16x8*)(dstb + c * 8) = *(const bf16x8*)(myl + c * 8);
    }
  } else {
#pragma unroll
    for (int m = 0; m < 8; ++m)
#pragma unroll
      for (int n = 0; n < 4; ++n)
#pragma unroll
        for (int jr = 0; jr < 4; ++jr) {
          int tl = m * 16 + ((l >> 4) << 2) + jr;
          int d = n * 16 + (l & 15);
          float val = acc[m][n][jr] + bcat[gcb + d];
          myl[d * 128 + (tl ^ ((d & 7) << 4))] = f2bf(val);
        }
    asm volatile("s_waitcnt lgkmcnt(0)" ::: "memory");
#pragma unroll
    for (int i = 0; i < 16; ++i) {
      int c = i * 64 + l;
      int d = c >> 4, off = (c & 15) * 8;
      bf16x8 v = *(const bf16x8*)(myl + d * 128 + (off ^ ((d & 7) << 4)));
      *(bf16x8*)(Vt + (((size_t)((b2 * 16 + h) * 64 + d)) << 11) + t0 + off) = v;
    }
  }
}

// ---------------------------------------------------------------------------
__global__ __launch_bounds__(512, 2) void outproj_kernel(
    const u16* __restrict__ attn, const u16* __restrict__ Wob,
    const float* __restrict__ bo, float* __restrict__ out) {
  __shared__ __align__(16) u16 lds[65536];
  const int m0 = blockIdx.y * 256, n0 = blockIdx.x * 256;
  f32x4 acc[8][4];
  gemm256_db(attn, Wob, m0, n0, lds, lds + 32768, acc);
  const int tid = threadIdx.x, l = tid & 63;
  const int wid = tid >> 6, wr = wid >> 2, wc = wid & 3;
#pragma unroll
  for (int m = 0; m < 8; ++m)
#pragma unroll
    for (int n = 0; n < 4; ++n)
#pragma unroll
      for (int jr = 0; jr < 4; ++jr) {
        int gr = m0 + wr * 128 + m * 16 + ((l >> 4) << 2) + jr;
        int gc = n0 + wc * 64 + n * 16 + (l & 15);
        out[(size_t)gr * 1024 + gc] = acc[m][n][jr] + bo[gc];
      }
}

// ---------------------------------------------------------------------------
// Flash attention (causal), swapped-operand 32x32 MFMA, P in registers.
// R9: 512 threads = 8 waves. Group g = wave>>2 handles kv tiles
// [g*(qb+1), g*(qb+1)+qb] for the SAME q rows (wave&3 selects 32 q-rows of
// the 128-row q-block). Per-group double-buffered staging; online-softmax
// merge of the two groups through LDS at the end.
__global__ __launch_bounds__(512) void attn_kernel(const u16* __restrict__ Q,
                                                   const u16* __restrict__ K,
                                                   const u16* __restrict__ Vt,
                                                   u16* __restrict__ out) {
  __shared__ __align__(16) u16 lK[2][2][4096];  // [group][buf][64x64]
  __shared__ __align__(16) u16 lV[2][2][4096];
  const int tid = threadIdx.x, l = tid & 63;
  const int w8 = tid >> 6;            // 0..7
  const int grp = w8 >> 2, w = w8 & 3;
  const int gtid = tid & 255;         // thread id within group
  const int n = blockIdx.x;
  // XCD grouping (n&7) + LPT: heavy qb first; pairs (n, n+256) sum constant.
  const int xcd = n & 7, j = n >> 3;
  const int bh = xcd * 4 + (j & 3);   // 0..31
  const int ji = j >> 2;              // 0..15
  const int qb = (ji < 8) ? (15 - ji) : (ji - 8);
  const int b = bh >> 4, h = bh & 15;
  const int lq = l & 31, hl = l >> 5;
  const int q0w = qb * 128 + w * 32;
  const int qg = q0w + lq;            // this lane's global q row

  const u16* qbase = Q + ((((size_t)bh) << 11) + qg) * 64 + hl * 8;
  bf16x8 qf[4];
#pragma unroll
  for (int kd = 0; kd < 4; ++kd) qf[kd] = *(const bf16x8*)(qbase + kd * 16);

  const f32x16 z16 = {0.f, 0.f, 0.f, 0.f, 0.f, 0.f, 0.f, 0.f,
                      0.f, 0.f, 0.f, 0.f, 0.f, 0.f, 0.f, 0.f};
  f32x16 oacc[2];  // O^T: rows d = dblk*32 + (r&3)+8*(r>>2)+4*hl, col q = lq
  oacc[0] = z16; oacc[1] = z16;
  float mi = -1e30f, li = 0.f;

  const int nth = qb + 1;             // tiles per group
  const int tb = grp * nth;           // my group's first tile

  // stage K [64 kv][64 d] and Vt [64 d][64 kv] for tile `it_` into group buf
#define STAGE_KV(it_, buf_)                                                        \
  {                                                                                \
    _Pragma("unroll") for (int r = 0; r < 2; ++r) {                                \
      int ch = r * 256 + gtid;                                                     \
      int row = ch >> 3, s = ch & 7;                                               \
      gload_lds16(                                                                 \
          K + ((((size_t)bh) << 11) + (it_) * 64 + row) * 64 + ((s ^ (row & 7)) << 3), \
          &lK[grp][buf_][0] + ch * 8);                                             \
    }                                                                              \
    _Pragma("unroll") for (int r = 0; r < 2; ++r) {                                \
      int ch = r * 256 + gtid;                                                     \
      int row = ch >> 3, s = ch & 7;                                               \
      gload_lds16(                                                                 \
          Vt + ((((size_t)bh) * 64 + row) << 11) + (it_) * 64 + ((s ^ (row & 7)) << 3), \
          &lV[grp][buf_][0] + ch * 8);                                             \
    }                                                                              \
  }

  STAGE_KV(tb, 0);  // prologue: my group's tile 0 in flight
  int cur = 0;

  for (int it = 0; it < nth; ++it) {
    const int tile = tb + it;
    const int kv0 = tile * 64;
    if (it + 1 < nth) {
      STAGE_KV(tile + 1, cur ^ 1);
      asm volatile("s_waitcnt vmcnt(4)" ::: "memory");
    } else {
      asm volatile("s_waitcnt vmcnt(0)" ::: "memory");
    }
    __builtin_amdgcn_s_barrier();

    const bool active = (kv0 <= q0w + 31);
    if (active) {
      const u16* pK = &lK[grp][cur][0];
      const u16* pV = &lV[grp][cur][0];

      // ---- S^T = K Q^T ----
      f32x16 sacc[2];
      sacc[0] = z16; sacc[1] = z16;
#pragma unroll
      for (int g = 0; g < 2; ++g) {
        int row = g * 32 + lq;
        int sw = row & 7;
#pragma unroll
        for (int kd = 0; kd < 4; ++kd) {
          bf16x8 kf = *(const bf16x8*)(pK + row * 64 + (((kd * 2 + hl) ^ sw) << 3));
          sacc[g] = __builtin_amdgcn_mfma_f32_32x32x16_bf16(kf, qf[kd], sacc[g], 0, 0, 0);
        }
      }

      // ---- causal mask ----
      if (kv0 + 63 > q0w) {
#pragma unroll
        for (int g = 0; g < 2; ++g)
#pragma unroll
          for (int r = 0; r < 16; ++r) {
            int kv = kv0 + g * 32 + (r & 3) + ((r >> 2) << 3) + hl * 4;
            if (kv > qg) sacc[g][r] = -1e30f;
          }
      }

      // ---- online softmax (exp2 domain) ----
      float mx[16];
#pragma unroll
      for (int r = 0; r < 16; ++r) mx[r] = fmaxf(sacc[0][r], sacc[1][r]);
#pragma unroll
      for (int s = 8; s > 0; s >>= 1)
#pragma unroll
        for (int r = 0; r < s; ++r) mx[r] = fmaxf(mx[r], mx[r + s]);
      float mt = fmaxf(mx[0], __shfl_xor(mx[0], 32, 64));

      if (!__all(mt <= mi + 8.0f)) {
        float mn = fmaxf(mi, mt);
        float al = EXP2(mi - mn);
        mi = mn;
#pragma unroll
        for (int dblk = 0; dblk < 2; ++dblk)
#pragma unroll
          for (int r = 0; r < 16; ++r) oacc[dblk][r] *= al;
        li *= al;
      }
#pragma unroll
      for (int g = 0; g < 2; ++g)
#pragma unroll
        for (int r = 0; r < 16; ++r) sacc[g][r] = EXP2(sacc[g][r] - mi);
      float sm[16];
#pragma unroll
      for (int r = 0; r < 16; ++r) sm[r] = sacc[0][r] + sacc[1][r];
#pragma unroll
      for (int s = 8; s > 0; s >>= 1)
#pragma unroll
        for (int r = 0; r < s; ++r) sm[r] += sm[r + s];
      float rs = sm[0] + __shfl_xor(sm[0], 32, 64);
      li += rs;

      // ---- P -> bf16 pairs; PV B-fragments via verified shfl_xor hl-mux ----
      u32 pw[2][8], px[2][8];
#pragma unroll
      for (int g = 0; g < 2; ++g)
#pragma unroll
        for (int i = 0; i < 8; ++i) {
          union { bf16_t h2[2]; u32 u; } pk;
          pk.h2[0] = (bf16_t)sacc[g][2 * i];
          pk.h2[1] = (bf16_t)sacc[g][2 * i + 1];
          pw[g][i] = pk.u;
        }
#pragma unroll
      for (int g = 0; g < 2; ++g)
#pragma unroll
        for (int i = 0; i < 8; ++i)
          px[g][i] = (u32)__shfl_xor((int)pw[g][i], 32, 64);

      bf16x8 pfrag[4];
#pragma unroll
      for (int km = 0; km < 4; ++km) {
        const int g = km >> 1, o = (km & 1) * 4;
        union { u32 u[4]; bf16x8 v; } f;
        f.u[0] = hl ? px[g][o + 2] : pw[g][o + 0];
        f.u[1] = hl ? px[g][o + 3] : pw[g][o + 1];
        f.u[2] = hl ? pw[g][o + 2] : px[g][o + 0];
        f.u[3] = hl ? pw[g][o + 3] : px[g][o + 1];
        pfrag[km] = f.v;
      }

      // ---- O^T += V^T P^T ----
#pragma unroll
      for (int dblk = 0; dblk < 2; ++dblk) {
        int row = dblk * 32 + lq;
        int sw = row & 7;
#pragma unroll
        for (int km = 0; km < 4; ++km) {
          bf16x8 vf = *(const bf16x8*)(pV + row * 64 + (((km * 2 + hl) ^ sw) << 3));
          oacc[dblk] = __builtin_amdgcn_mfma_f32_32x32x16_bf16(vf, pfrag[km],
                                                              oacc[dblk], 0, 0, 0);
        }
      }
    }
    __builtin_amdgcn_s_barrier();
    cur ^= 1;
  }
#undef STAGE_KV

  // ---- merge group 1 into group 0 through LDS (staging buffers are dead) ----
  float* cb = (float*)&lK[0][0][0];  // 32 KB: per wave w, 64x32 f32 O^T panel
  float* ml = (float*)&lV[0][0][0];  // m/l per q row
  if (grp == 1) {
    float* myo = cb + w * 2048;
#pragma unroll
    for (int dblk = 0; dblk < 2; ++dblk)
#pragma unroll
      for (int r = 0; r < 16; ++r) {
        int d = dblk * 32 + (r & 3) + ((r >> 2) << 3) + hl * 4;
        myo[d * 32 + lq] = oacc[dblk][r];
      }
    ml[w * 64 + lq] = mi;       // hl halves write identical values
    ml[w * 64 + 32 + lq] = li;
  }
  asm volatile("s_waitcnt lgkmcnt(0)" ::: "memory");
  __builtin_amdgcn_s_barrier();

  if (grp == 0) {
    const float m1 = ml[w * 64 + lq];
    const float l1 = ml[w * 64 + 32 + lq];
    const float* po = cb + w * 2048;
    const float m = fmaxf(mi, m1);
    const float w0 = EXP2(mi - m), w1 = EXP2(m1 - m);
    const float inv = 1.0f / (li * w0 + l1 * w1);
    const size_t rowbase = ((size_t)(b * 2048 + qg)) * 1024 + h * 64;
#pragma unroll
    for (int dblk = 0; dblk < 2; ++dblk)
#pragma unroll
      for (int g4 = 0; g4 < 4; ++g4) {
        ushort4 st;
#pragma unroll
        for (int jj = 0; jj < 4; ++jj) {
          int r = g4 * 4 + jj;
          int d = dblk * 32 + g4 * 8 + hl * 4 + jj;
          float o = (oacc[dblk][r] * w0 + po[d * 32 + lq] * w1) * inv;
          ((u16*)&st)[jj] = f2bf(o);
        }
        *(ushort4*)((u16*)out + rowbase + dblk * 32 + g4 * 8 + hl * 4) = st;
      }
  }
}

// ---------------------------------------------------------------------------
extern "C" void kernel_launch(void* const* d_in, const int* in_sizes, int n_in,
                              void* d_out, int out_size, void* d_ws, size_t ws_size,
                              hipStream_t stream) {
  const float* x  = (const float*)d_in[0];
  const float* Wq = (const float*)d_in[1];
  const float* bq = (const float*)d_in[2];
  const float* Wk = (const float*)d_in[3];
  const float* bk = (const float*)d_in[4];
  const float* Wv = (const float*)d_in[5];
  const float* bv = (const float*)d_in[6];
  const float* Wo = (const float*)d_in[7];
  const float* bo = (const float*)d_in[8];
  float* out = (float*)d_out;

  char* ws = (char*)d_ws;
  u16* xb    = (u16*)(ws);                        // 8 MB
  u16* Wqkvo = (u16*)(ws + (8ull << 20));         // 8 MB: Wq|Wk|Wv|Wo contiguous
  u16* Wob   = Wqkvo + 3 * 1048576;
  u16* Qr  = (u16*)(ws + (16ull << 20));          // 8 MB  [B,H,T,D] (pre-scaled)
  u16* Kr  = (u16*)(ws + (24ull << 20));          // 8 MB  [B,H,T,D]
  u16* Vt  = (u16*)(ws + (32ull << 20));          // 8 MB  [B,H,D,T]
  u16* At  = (u16*)(ws + (40ull << 20));          // 8 MB  attn out bf16 [B,T,C]
  float* tab  = (float*)(ws + (48ull << 20));     // 512 KB rope table
  float* bcat = (float*)(ws + (48ull << 20) + (512ull << 10));  // 12 KB

  prep_kernel<<<dim3(8460), dim3(256), 0, stream>>>(x, Wq, Wk, Wv, Wo, bq, bk, bv,
                                                    xb, Wqkvo, tab, bcat);
  qkv_kernel<<<dim3(12, 16), dim3(512), 0, stream>>>(xb, Wqkvo, bcat, tab,
                                                     Qr, Kr, Vt);
  attn_kernel<<<dim3(512), dim3(512), 0, stream>>>(Qr, Kr, Vt, At);
  outproj_kernel<<<dim3(4, 16), dim3(512), 0, stream>>>(At, Wob, bo, out);
}